// Round 12
// baseline (580.085 us; speedup 1.0000x reference)
//
#include <hip/hip_runtime.h>

// B=4 S=1024 D=1024 H=16 HD=64 E=8 TOPK=2 F=4096 ; tokens N=4096
typedef unsigned short u16;
typedef _Float16 f16x8 __attribute__((ext_vector_type(8)));
typedef __bf16   bf16x8 __attribute__((ext_vector_type(8)));
typedef float    f32x4 __attribute__((ext_vector_type(4)));

struct __align__(8) U16x4 { u16 v[4]; };

#define MAXT 72
#define MAXT2 136

__device__ __forceinline__ u16 f2b(float f) {            // f32 -> bf16 RNE bits
  unsigned u = __builtin_bit_cast(unsigned, f);
  return (u16)((u + 0x7FFFu + ((u >> 16) & 1u)) >> 16);
}
__device__ __forceinline__ u16 f2h(float f) { return __builtin_bit_cast(u16, (_Float16)f); }
__device__ __forceinline__ u16 f2h_lo(float f) {
  _Float16 h = (_Float16)f;
  return __builtin_bit_cast(u16, (_Float16)(f - (float)h));
}
__device__ __forceinline__ void llds16(const void* g, void* l) {
  __builtin_amdgcn_global_load_lds((const __attribute__((address_space(1))) unsigned int*)g,
                                   (__attribute__((address_space(3))) unsigned int*)l, 16, 0, 0);
}
__device__ __forceinline__ f32x4 mmf(f16x8 a, f16x8 b, f32x4 c) {
  return __builtin_amdgcn_mfma_f32_16x16x32_f16(a, b, c, 0, 0, 0);
}
__device__ __forceinline__ f32x4 mmb(bf16x8 a, bf16x8 b, f32x4 c) {
  return __builtin_amdgcn_mfma_f32_16x16x32_bf16(a, b, c, 0, 0, 0);
}

// ---------------- transpose + convert: src [R,C] f32 -> dst [C,R] f16(hi/lo) or bf16 ----
template<int OUT> // 0: f16 split pair, 1: bf16 single
__global__ __launch_bounds__(256) void transpose_kernel(const float* __restrict__ src,
                                                        u16* __restrict__ d0, u16* __restrict__ d1,
                                                        int R, int C) {
  __shared__ float t[32][33];
  long zo = (long)blockIdx.z * R * C;
  int r0 = blockIdx.y << 5, c0 = blockIdx.x << 5;
  int tid = threadIdx.x;
  {
    int r = tid >> 3, c = (tid & 7) << 2;
    float4 v = *(const float4*)(src + zo + (long)(r0 + r) * C + c0 + c);
    t[r][c] = v.x; t[r][c + 1] = v.y; t[r][c + 2] = v.z; t[r][c + 3] = v.w;
  }
  __syncthreads();
  int c = tid >> 3, rg = (tid & 7) << 2;
  long o = zo + (long)(c0 + c) * R + r0 + rg;
  U16x4 a, b2;
#pragma unroll
  for (int i = 0; i < 4; i++) {
    float f = t[rg + i][c];
    if (OUT == 0) { a.v[i] = f2h(f); b2.v[i] = f2h_lo(f); }
    else a.v[i] = f2b(f);
  }
  *(U16x4*)(d0 + o) = a;
  if (OUT == 0) *(U16x4*)(d1 + o) = b2;
}

// ---------------- Wg [1024,8] -> WgT [8,1024] (tiny, for coalesced gate loads) ---------
__global__ __launch_bounds__(256) void wg_transpose(const float* __restrict__ Wg,
                                                    float* __restrict__ WgT) {
  int idx = blockIdx.x * 256 + threadIdx.x;   // 8192 elements
  int d = idx >> 3, e = idx & 7;
  WgT[e * 1024 + d] = Wg[idx];
}

// ---------------- LayerNorm row kernel (LN1 only; LN2 fused into gate) ----------------
__global__ __launch_bounds__(256) void ln_kernel(const float* __restrict__ x, const float* __restrict__ g,
                                                 const float* __restrict__ bt,
                                                 u16* __restrict__ d0, u16* __restrict__ d1) {
  long row = blockIdx.x;
  int tid = threadIdx.x;
  const float4 v = *(const float4*)(x + (row << 10) + (tid << 2));
  float s = v.x + v.y + v.z + v.w;
  float q = v.x * v.x + v.y * v.y + v.z * v.z + v.w * v.w;
#pragma unroll
  for (int m = 1; m < 64; m <<= 1) { s += __shfl_xor(s, m); q += __shfl_xor(q, m); }
  __shared__ float rs[4], rq[4];
  if ((tid & 63) == 0) { rs[tid >> 6] = s; rq[tid >> 6] = q; }
  __syncthreads();
  s = rs[0] + rs[1] + rs[2] + rs[3];
  q = rq[0] + rq[1] + rq[2] + rq[3];
  float mu = s * (1.f / 1024.f);
  float inv = 1.f / sqrtf(q * (1.f / 1024.f) - mu * mu + 1e-5f);
  float4 gg = *(const float4*)(g + (tid << 2));
  float4 bb = *(const float4*)(bt + (tid << 2));
  float o0 = (v.x - mu) * inv * gg.x + bb.x;
  float o1 = (v.y - mu) * inv * gg.y + bb.y;
  float o2 = (v.z - mu) * inv * gg.z + bb.z;
  float o3 = (v.w - mu) * inv * gg.w + bb.w;
  long o = (row << 10) + (tid << 2);
  U16x4 a, b2;
  a.v[0] = f2h(o0); a.v[1] = f2h(o1); a.v[2] = f2h(o2); a.v[3] = f2h(o3);
  b2.v[0] = f2h_lo(o0); b2.v[1] = f2h_lo(o1); b2.v[2] = f2h_lo(o2); b2.v[3] = f2h_lo(o3);
  *(U16x4*)(d0 + o) = a; *(U16x4*)(d1 + o) = b2;
}

// ------- unified tiled GEMM, BMxTN xK BK=64, A[M,K] x Bt[N,K], 512 thr / 8 waves -------
// MODE 0: split f16 x3 -> f32 out (QKV), BM=128 TN=128, waves 2x4.
// MODE 1: split f16 x3 -> f32 + resid (Wo), BM=128 TN=64, waves 2x4.
// MODE 2: bf16, A gathered via lists -> gelu -> bf16 (FFN1), BM=128 TN=128, XCD-chunked.
// MODE 3: bf16, A direct grouped -> scatter f32 w*acc (FFN2), BM=64 TN=128, waves 1x8,
//         24KB LDS, 64-row tiles -> grid 1088 = 4.25 blocks/CU for latency hiding.
template<int MODE>
__global__ __launch_bounds__(512, 1) void gemm_kernel(
    const u16* __restrict__ Ah, const u16* __restrict__ Al,
    const u16* __restrict__ Bh, const u16* __restrict__ Bl,
    int K, int ldc, int Nexp,
    const int* __restrict__ lists, const int* __restrict__ tile_e,
    const int* __restrict__ tile_b, const int* __restrict__ tile_c,
    float* __restrict__ outf, u16* __restrict__ outb,
    const float* __restrict__ resid, const float* __restrict__ slotw) {
  constexpr bool SPLIT = (MODE < 2);
  constexpr int TN = (MODE == 1) ? 64 : 128;     // tile N
  constexpr int BM = (MODE == 3) ? 64 : 128;     // tile M
  constexpr int NF = (MODE == 3) ? 1 : (TN >> 6); // n-frags per wave
  constexpr int NA = BM >> 6;                    // A staging chunks per thread
  constexpr int NB = TN >> 6;                    // B staging chunks per thread
  constexpr int ABYT = SPLIT ? 16384 : BM * 128;
  constexpr int SMEM = SPLIT ? 65536 : (BM + TN) * 128;
  __shared__ __align__(16) char smem[SMEM];
  char* pAh = smem;
  char* pBh = smem + ABYT;
  char* pAl = smem + 32768;   // SPLIT only
  char* pBl = smem + 49152;   // SPLIT only
  const int tid = threadIdx.x, w = tid >> 6, l = tid & 63;
  int n0;
  int grbase = 0, rowsv = BM;
  long m0 = 0;
  if (MODE >= 2) {
    // Chunked XCD swizzle: XCD c owns TPX consecutive y-tiles (A-panel sharers colocate
    // on one L2; an expert's tiles stay mostly within one XCD for W reuse).
    constexpr int TPX = (MODE == 3) ? 17 : 9;
    int lin = blockIdx.x;
    int c = lin & 7, k = lin >> 3;
    int ty = c * TPX + (k % TPX);
    int tx = k / TPX;
    n0 = tx * TN;
    int e = tile_e[ty];
    if (e < 0) return;
    grbase = tile_b[ty];
    rowsv = tile_c[ty];
    Bh += (long)e * Nexp * K;
  } else {
    n0 = blockIdx.x * TN;
    m0 = (long)blockIdx.y << 7;
  }

  const u16 *as0[2], *as1[2], *bs0[2], *bs1[2];
  int dstA[2], dstB[2];
#pragma unroll
  for (int i = 0; i < NA; i++) {       // A: BM*8 chunks of 16B over 512 threads
    int chunk = i * 512 + tid;
    int row = chunk >> 3, c16 = chunk & 7;
    int scol = (c16 << 4) ^ ((row & 7) << 4);   // pre-swizzled source byte col
    dstA[i] = chunk << 4;
    long ar;
    if (MODE == 2) {
      int vlu = lists[(row < rowsv) ? (grbase + row) : grbase];
      ar = (long)(vlu >> 1);
    } else if (MODE == 3) {
      ar = grbase + ((row < rowsv) ? row : 0);
    } else {
      ar = m0 + row;
    }
    long ao = ar * (long)K + (scol >> 1);
    as0[i] = Ah + ao;
    if (SPLIT) as1[i] = Al + ao;
  }
#pragma unroll
  for (int i = 0; i < NB; i++) {       // B: TN*8 chunks of 16B over 512 threads
    int chunk = i * 512 + tid;
    int row = chunk >> 3, c16 = chunk & 7;
    int scol = (c16 << 4) ^ ((row & 7) << 4);
    dstB[i] = chunk << 4;
    long bo = (long)(n0 + row) * K + (scol >> 1);
    bs0[i] = Bh + bo;
    if (SPLIT) bs1[i] = Bl + bo;
  }

  f32x4 acc[4][NF];
#pragma unroll
  for (int i = 0; i < 4; i++)
#pragma unroll
    for (int j = 0; j < NF; j++) acc[i][j] = (f32x4){0.f, 0.f, 0.f, 0.f};

  int wr, wc;
  if (MODE == 3) { wr = 0; wc = w << 4; }               // 1x8 waves, 64x16 each
  else { wr = (w >> 2) << 6; wc = (w & 3) * (TN / 4); } // 2x4 waves
  const int nkt = K >> 6;
  for (int kt = 0; kt < nkt; ++kt) {
    if (kt) __syncthreads();
#pragma unroll
    for (int i = 0; i < NA; i++) {
      llds16(as0[i] + (kt << 6), pAh + dstA[i]);
      if (SPLIT) llds16(as1[i] + (kt << 6), pAl + dstA[i]);
    }
#pragma unroll
    for (int i = 0; i < NB; i++) {
      llds16(bs0[i] + (kt << 6), pBh + dstB[i]);
      if (SPLIT) llds16(bs1[i] + (kt << 6), pBl + dstB[i]);
    }
    __syncthreads();
#pragma unroll
    for (int kc = 0; kc < 2; kc++) {
      const int kby = (kc << 6) + ((l >> 4) << 4);
      int aoff[4], boff[NF];
#pragma unroll
      for (int mf = 0; mf < 4; mf++) { int row = wr + (mf << 4) + (l & 15); aoff[mf] = (row << 7) + (kby ^ ((row & 7) << 4)); }
#pragma unroll
      for (int nf = 0; nf < NF; nf++) { int row = wc + (nf << 4) + (l & 15); boff[nf] = (row << 7) + (kby ^ ((row & 7) << 4)); }
      if (SPLIT) {
        f16x8 a0[4], a1[4], b0[NF], b1[NF];
#pragma unroll
        for (int mf = 0; mf < 4; mf++) {
          a0[mf] = *(const f16x8*)(pAh + aoff[mf]);
          a1[mf] = *(const f16x8*)(pAl + aoff[mf]);
        }
#pragma unroll
        for (int nf = 0; nf < NF; nf++) {
          b0[nf] = *(const f16x8*)(pBh + boff[nf]);
          b1[nf] = *(const f16x8*)(pBl + boff[nf]);
        }
#pragma unroll
        for (int mf = 0; mf < 4; mf++)
#pragma unroll
          for (int nf = 0; nf < NF; nf++) {
            acc[mf][nf] = mmf(a0[mf], b0[nf], acc[mf][nf]);
            acc[mf][nf] = mmf(a0[mf], b1[nf], acc[mf][nf]);
            acc[mf][nf] = mmf(a1[mf], b0[nf], acc[mf][nf]);
          }
      } else {
        bf16x8 a0[4], b0[NF];
#pragma unroll
        for (int mf = 0; mf < 4; mf++) a0[mf] = *(const bf16x8*)(pAh + aoff[mf]);
#pragma unroll
        for (int nf = 0; nf < NF; nf++) b0[nf] = *(const bf16x8*)(pBh + boff[nf]);
#pragma unroll
        for (int mf = 0; mf < 4; mf++)
#pragma unroll
          for (int nf = 0; nf < NF; nf++) acc[mf][nf] = mmb(a0[mf], b0[nf], acc[mf][nf]);
      }
    }
  }

  // epilogue: C/D layout col = lane&15, row = (lane>>4)*4 + reg
#pragma unroll
  for (int mf = 0; mf < 4; mf++) {
#pragma unroll
    for (int r = 0; r < 4; r++) {
      const int lrow = wr + (mf << 4) + ((l >> 4) << 2) + r;
      if (MODE >= 2 && lrow >= rowsv) continue;
      float gw = 0.f; long orow = 0;
      if (MODE == 3) { int gr = grbase + lrow; orow = (long)lists[gr] * ldc; gw = slotw[gr]; }
#pragma unroll
      for (int nf = 0; nf < NF; nf++) {
        const int col = n0 + wc + (nf << 4) + (l & 15);
        float v = acc[mf][nf][r];
        if (MODE == 0) {
          outf[(m0 + lrow) * (long)ldc + col] = v;
        } else if (MODE == 1) {
          long ix = (m0 + lrow) * (long)ldc + col;
          outf[ix] = v + resid[ix];
        } else if (MODE == 2) {
          // gelu(v) = v * sigmoid(1.5957691 v + 0.0713549 v^3)  (exact tanh-form identity)
          float t = v * (1.59576912f + 0.07135539f * v * v);
          float u = v * __builtin_amdgcn_rcpf(1.f + __expf(-t));
          outb[(long)(grbase + lrow) * ldc + col] = f2b(u);
        } else {
          outf[orow + col] = v * gw;
        }
      }
    }
  }
}

// ---------------- K/V pre-convert: per (b,h) planes Kh/Kl [1024][64], Vth/Vtl [64][1024] ----
__global__ __launch_bounds__(256) void kv_prep(const float* __restrict__ qkv,
                                               u16* __restrict__ Kh, u16* __restrict__ Kl,
                                               u16* __restrict__ Vth, u16* __restrict__ Vtl) {
  __shared__ float t[64][65];
  const int tid = threadIdx.x;
  const int kb = blockIdx.x, h = blockIdx.y, b = blockIdx.z;
  const long bb = ((long)b) << 10;
  const int hoff = h << 6;
  const long head = ((long)(b * 16 + h)) << 16;   // 65536 elems per head-plane
  {
    int rr = tid >> 4, c = (tid & 15) << 2;
#pragma unroll
    for (int p = 0; p < 4; p++) {
      int r = rr + p * 16;
      const float* base = qkv + (bb + kb * 64 + r) * 3072 + hoff + c;
      float4 u = *(const float4*)(base + 1024);
      U16x4 a, lo;
      a.v[0] = f2h(u.x); a.v[1] = f2h(u.y); a.v[2] = f2h(u.z); a.v[3] = f2h(u.w);
      lo.v[0] = f2h_lo(u.x); lo.v[1] = f2h_lo(u.y); lo.v[2] = f2h_lo(u.z); lo.v[3] = f2h_lo(u.w);
      long o = head + (long)(kb * 64 + r) * 64 + c;
      *(U16x4*)(Kh + o) = a; *(U16x4*)(Kl + o) = lo;
      float4 v = *(const float4*)(base + 2048);
      t[r][c] = v.x; t[r][c + 1] = v.y; t[r][c + 2] = v.z; t[r][c + 3] = v.w;
    }
  }
  __syncthreads();
  {
    int hd = tid >> 2, k4 = (tid & 3) << 4;
#pragma unroll
    for (int q = 0; q < 4; q++) {
      U16x4 a, lo;
#pragma unroll
      for (int j = 0; j < 4; j++) {
        float f = t[k4 + q * 4 + j][hd];
        a.v[j] = f2h(f); lo.v[j] = f2h_lo(f);
      }
      long o = head + (long)hd * 1024 + kb * 64 + k4 + q * 4;
      *(U16x4*)(Vth + o) = a; *(U16x4*)(Vtl + o) = lo;
    }
  }
}

// ---------------- flash attention v2: prepped K/V planes, llds staging, balanced pairing ----
__global__ __launch_bounds__(256, 1) void attn_kernel(const float* __restrict__ qkv,
                                                      const u16* __restrict__ Kh, const u16* __restrict__ Kl,
                                                      const u16* __restrict__ Vth, const u16* __restrict__ Vtl,
                                                      u16* __restrict__ oh, u16* __restrict__ ol) {
  __shared__ u16 kh[4096], kl[4096];       // K tile [64 key][64 hd], swizzled
  __shared__ u16 vh[4096], vl[4096];       // V^T tile [64 hd][64 key], swizzled
  __shared__ u16 ph[4][1024], pl[4][1024]; // per-wave P [16 m][64 k]
  const int tid = threadIdx.x, w = tid >> 6, l = tid & 63;
  const int qbi = blockIdx.x, hh_ = blockIdx.y, b = blockIdx.z;
  const long bb = ((long)b) << 10;
  const int hoff = hh_ << 6;
  const long head = ((long)(b * 16 + hh_)) << 16;

  // staging descriptors (2 chunks of 16B per thread per plane)
  const u16 *ks0[2], *ks1[2], *vs0[2], *vs1[2];
  int db[2];
#pragma unroll
  for (int i = 0; i < 2; i++) {
    int chunk = i * 256 + tid;
    int row = chunk >> 3, c16 = chunk & 7;
    int sc = ((c16 << 4) ^ ((row & 7) << 4)) >> 1;
    db[i] = chunk << 4;
    ks0[i] = Kh + head + row * 64 + sc;
    ks1[i] = Kl + head + row * 64 + sc;
    vs0[i] = Vth + head + (long)row * 1024 + sc;
    vs1[i] = Vtl + head + (long)row * 1024 + sc;
  }

  for (int pass = 0; pass < 2; ++pass) {
    const int qb = (pass ? qbi : (15 - qbi)) << 6;   // long pass first; total 17 tiles/block
    // load Q fragments (split f16)
    f16x8 q0[2], q1[2];
    {
      const long qrow = bb + qb + (w << 4) + (l & 15);
      const float* qp = qkv + qrow * 3072 + hoff + ((l >> 4) << 3);
#pragma unroll
      for (int kc = 0; kc < 2; kc++) {
        float4 u0 = *(const float4*)(qp + (kc << 5));
        float4 u1 = *(const float4*)(qp + (kc << 5) + 4);
        float vv[8] = {u0.x, u0.y, u0.z, u0.w, u1.x, u1.y, u1.z, u1.w};
#pragma unroll
        for (int j = 0; j < 8; j++) {
          _Float16 hi = (_Float16)vv[j];
          q0[kc][j] = hi;
          q1[kc][j] = (_Float16)(vv[j] - (float)hi);
        }
      }
    }

    f32x4 o[4];
#pragma unroll
    for (int nf = 0; nf < 4; nf++) o[nf] = (f32x4){0.f, 0.f, 0.f, 0.f};
    float mr[4] = {-1e30f, -1e30f, -1e30f, -1e30f};
    float lr[4] = {0.f, 0.f, 0.f, 0.f};
    const int ktm = qb >> 6;

    for (int kt = 0; kt <= ktm; ++kt) {
      __syncthreads();
#pragma unroll
      for (int i = 0; i < 2; i++) {
        llds16(ks0[i] + (kt << 12), (char*)kh + db[i]);
        llds16(ks1[i] + (kt << 12), (char*)kl + db[i]);
        llds16(vs0[i] + (kt << 6), (char*)vh + db[i]);
        llds16(vs1[i] + (kt << 6), (char*)vl + db[i]);
      }
      __syncthreads();

      // QK^T (split x3)
      f32x4 s[4];
#pragma unroll
      for (int nf = 0; nf < 4; nf++) s[nf] = (f32x4){0.f, 0.f, 0.f, 0.f};
#pragma unroll
      for (int kc = 0; kc < 2; kc++) {
        const int kby = (kc << 6) + ((l >> 4) << 4);
#pragma unroll
        for (int nf = 0; nf < 4; nf++) {
          int row = (nf << 4) + (l & 15);
          int off = (row << 7) + (kby ^ ((row & 7) << 4));
          f16x8 k0 = *(const f16x8*)((const char*)kh + off);
          f16x8 k1 = *(const f16x8*)((const char*)kl + off);
          s[nf] = mmf(q0[kc], k0, s[nf]);
          s[nf] = mmf(q0[kc], k1, s[nf]);
          s[nf] = mmf(q1[kc], k0, s[nf]);
        }
      }
      const bool lastt = (kt == ktm);
#pragma unroll
      for (int nf = 0; nf < 4; nf++)
#pragma unroll
        for (int r = 0; r < 4; r++) {
          float sc = s[nf][r] * 0.125f;
          if (lastt) {
            int keyg = (kt << 6) + (nf << 4) + (l & 15);
            int qg = qb + (w << 4) + ((l >> 4) << 2) + r;
            if (keyg > qg) sc = -1e30f;
          }
          s[nf][r] = sc;
        }
      float alpha[4];
#pragma unroll
      for (int r = 0; r < 4; r++) {
        float mx = fmaxf(fmaxf(s[0][r], s[1][r]), fmaxf(s[2][r], s[3][r]));
        mx = fmaxf(mx, __shfl_xor(mx, 1));
        mx = fmaxf(mx, __shfl_xor(mx, 2));
        mx = fmaxf(mx, __shfl_xor(mx, 4));
        mx = fmaxf(mx, __shfl_xor(mx, 8));
        float mn = fmaxf(mr[r], mx);
        float su = 0.f;
#pragma unroll
        for (int nf = 0; nf < 4; nf++) { float pv = __expf(s[nf][r] - mn); s[nf][r] = pv; su += pv; }
        su += __shfl_xor(su, 1); su += __shfl_xor(su, 2);
        su += __shfl_xor(su, 4); su += __shfl_xor(su, 8);
        alpha[r] = __expf(mr[r] - mn);
        lr[r] = lr[r] * alpha[r] + su;
        mr[r] = mn;
      }
#pragma unroll
      for (int nf = 0; nf < 4; nf++)
#pragma unroll
        for (int r = 0; r < 4; r++) o[nf][r] *= alpha[r];
      // write P (hi/lo) to per-wave LDS
#pragma unroll
      for (int nf = 0; nf < 4; nf++)
#pragma unroll
        for (int r = 0; r < 4; r++) {
          int m = ((l >> 4) << 2) + r, k = (nf << 4) + (l & 15);
          int off = (m << 7) + ((k << 1) ^ ((m & 7) << 4));
          float pv = s[nf][r];
          _Float16 hi = (_Float16)pv;
          *(u16*)((char*)&ph[w][0] + off) = __builtin_bit_cast(u16, hi);
          *(u16*)((char*)&pl[w][0] + off) = __builtin_bit_cast(u16, (_Float16)(pv - (float)hi));
        }
      // PV (split x3)
#pragma unroll
      for (int kc = 0; kc < 2; kc++) {
        const int kby = (kc << 6) + ((l >> 4) << 4);
        const int mm = l & 15;
        int poff = (mm << 7) + (kby ^ ((mm & 7) << 4));
        f16x8 p0 = *(const f16x8*)((const char*)&ph[w][0] + poff);
        f16x8 p1 = *(const f16x8*)((const char*)&pl[w][0] + poff);
#pragma unroll
        for (int nf = 0; nf < 4; nf++) {
          int row = (nf << 4) + (l & 15);
          int off = (row << 7) + (kby ^ ((row & 7) << 4));
          f16x8 v0 = *(const f16x8*)((const char*)vh + off);
          f16x8 v1 = *(const f16x8*)((const char*)vl + off);
          o[nf] = mmf(p0, v0, o[nf]);
          o[nf] = mmf(p0, v1, o[nf]);
          o[nf] = mmf(p1, v0, o[nf]);
        }
      }
    }
    // store O split to f16 planes
#pragma unroll
    for (int nf = 0; nf < 4; nf++)
#pragma unroll
      for (int r = 0; r < 4; r++) {
        int lrow = (w << 4) + ((l >> 4) << 2) + r;
        float v = o[nf][r] / lr[r];
        long ix = (bb + qb + lrow) * 1024 + hoff + (nf << 4) + (l & 15);
        _Float16 hi = (_Float16)v;
        oh[ix] = __builtin_bit_cast(u16, hi);
        ol[ix] = __builtin_bit_cast(u16, (_Float16)(v - (float)hi));
      }
  }
}

// ------- gating v2: f32 LN + logits (WgT coalesced) + top2, fused LN2 out, NO atomics ----
__global__ __launch_bounds__(256) void gate_kernel(const float* __restrict__ xr, const float* __restrict__ g,
                                                   const float* __restrict__ b, const float* __restrict__ WgT,
                                                   int* __restrict__ tok_e, float* __restrict__ tok_w,
                                                   u16* __restrict__ moe) {
  int w = threadIdx.x >> 6, l = threadIdx.x & 63;
  long t = (long)blockIdx.x * 4 + w;
  const float* row = xr + (t << 10);
  float4 xv[4]; float s = 0.f, q = 0.f;
#pragma unroll
  for (int i = 0; i < 4; i++) {
    float4 v = *(const float4*)(row + (i << 8) + (l << 2));
    xv[i] = v;
    s += v.x + v.y + v.z + v.w;
    q += v.x * v.x + v.y * v.y + v.z * v.z + v.w * v.w;
  }
#pragma unroll
  for (int m = 1; m < 64; m <<= 1) { s += __shfl_xor(s, m); q += __shfl_xor(q, m); }
  float mu = s * (1.f / 1024.f);
  float inv = 1.f / sqrtf(q * (1.f / 1024.f) - mu * mu + 1e-5f);
  float acc[8] = {0.f, 0.f, 0.f, 0.f, 0.f, 0.f, 0.f, 0.f};
#pragma unroll
  for (int i = 0; i < 4; i++) {
    int d0 = (i << 8) + (l << 2);
    float4 gg = *(const float4*)(g + d0);
    float4 bb = *(const float4*)(b + d0);
    float x0 = (xv[i].x - mu) * inv * gg.x + bb.x;
    float x1 = (xv[i].y - mu) * inv * gg.y + bb.y;
    float x2 = (xv[i].z - mu) * inv * gg.z + bb.z;
    float x3 = (xv[i].w - mu) * inv * gg.w + bb.w;
    U16x4 st;
    st.v[0] = f2b(x0); st.v[1] = f2b(x1); st.v[2] = f2b(x2); st.v[3] = f2b(x3);
    *(U16x4*)(moe + (t << 10) + d0) = st;
#pragma unroll
    for (int e = 0; e < 8; e++) {
      float4 wq = *(const float4*)(WgT + (e << 10) + d0);
      acc[e] += x0 * wq.x + x1 * wq.y + x2 * wq.z + x3 * wq.w;
    }
  }
#pragma unroll
  for (int e = 0; e < 8; e++)
#pragma unroll
    for (int m = 1; m < 64; m <<= 1) acc[e] += __shfl_xor(acc[e], m);
  if (l == 0) {
    int e0 = 0; float v0 = acc[0];
#pragma unroll
    for (int e = 1; e < 8; e++) if (acc[e] > v0) { v0 = acc[e]; e0 = e; }
    int e1 = (e0 == 0) ? 1 : 0; float v1 = acc[e1];
#pragma unroll
    for (int e = 0; e < 8; e++) if (e != e0 && acc[e] > v1) { v1 = acc[e]; e1 = e; }
    float w0 = 1.f / (1.f + __expf(v1 - v0));
    tok_e[t * 2] = e0; tok_e[t * 2 + 1] = e1;
    tok_w[t * 2] = w0; tok_w[t * 2 + 1] = 1.f - w0;
  }
}

// ------- plan v3: histogram tok_e; emit BOTH 128-row tiles (FFN1) and 64-row tiles (FFN2) --
__global__ __launch_bounds__(256) void plan_kernel(const int* __restrict__ tok_e, int* __restrict__ cursor,
                                                   int* __restrict__ tile_e, int* __restrict__ tile_b,
                                                   int* __restrict__ tile_c,
                                                   int* __restrict__ tile2_e, int* __restrict__ tile2_b,
                                                   int* __restrict__ tile2_c) {
  __shared__ int wc[4][8];
  int tid = threadIdx.x, w = tid >> 6, l = tid & 63;
  int c0 = 0, c1 = 0, c2 = 0, c3 = 0, c4 = 0, c5 = 0, c6 = 0, c7 = 0;
  for (int k = 0; k < 32; k++) {
    int v = tok_e[(w << 11) + (k << 6) + l];
    c0 += (v == 0); c1 += (v == 1); c2 += (v == 2); c3 += (v == 3);
    c4 += (v == 4); c5 += (v == 5); c6 += (v == 6); c7 += (v == 7);
  }
#pragma unroll
  for (int m = 1; m < 64; m <<= 1) {
    c0 += __shfl_xor(c0, m); c1 += __shfl_xor(c1, m); c2 += __shfl_xor(c2, m); c3 += __shfl_xor(c3, m);
    c4 += __shfl_xor(c4, m); c5 += __shfl_xor(c5, m); c6 += __shfl_xor(c6, m); c7 += __shfl_xor(c7, m);
  }
  if (l == 0) {
    wc[w][0] = c0; wc[w][1] = c1; wc[w][2] = c2; wc[w][3] = c3;
    wc[w][4] = c4; wc[w][5] = c5; wc[w][6] = c6; wc[w][7] = c7;
  }
  __syncthreads();
  if (tid == 0) {
    int o = 0, t1 = 0, t2 = 0;
    for (int e = 0; e < 8; e++) {
      cursor[e] = o;
      int cc = wc[0][e] + wc[1][e] + wc[2][e] + wc[3][e];
      for (int i = 0; i < cc; i += 128) {
        tile_e[t1] = e; tile_b[t1] = o + i; tile_c[t1] = (cc - i < 128) ? (cc - i) : 128; t1++;
      }
      for (int i = 0; i < cc; i += 64) {
        tile2_e[t2] = e; tile2_b[t2] = o + i; tile2_c[t2] = (cc - i < 64) ? (cc - i) : 64; t2++;
      }
      o += cc;
    }
    for (; t1 < MAXT; t1++) tile_e[t1] = -1;
    for (; t2 < MAXT2; t2++) tile2_e[t2] = -1;
  }
}

__global__ __launch_bounds__(256) void scatter_kernel(const int* __restrict__ tok_e, const float* __restrict__ tok_w,
                                                      int* __restrict__ cursor, int* __restrict__ lists,
                                                      float* __restrict__ slotw) {
  int t = blockIdx.x * 256 + threadIdx.x;
#pragma unroll
  for (int s = 0; s < 2; s++) {
    int e = tok_e[t * 2 + s];
    int pos = atomicAdd(&cursor[e], 1);
    lists[pos] = t * 2 + s;
    slotw[pos] = tok_w[t * 2 + s];
  }
}

__global__ __launch_bounds__(256) void combine_kernel(float* __restrict__ out, const float* __restrict__ yp) {
  long i = (long)blockIdx.x * 256 + threadIdx.x;  // float4 index over 4M floats
  long n = i >> 8;
  long d = i & 255;
  float4 o = *(float4*)(out + (i << 2));
  const float4 a = *(const float4*)(yp + ((n * 2) << 10) + (d << 2));
  const float4 b = *(const float4*)(yp + ((n * 2 + 1) << 10) + (d << 2));
  o.x += a.x + b.x; o.y += a.y + b.y; o.z += a.z + b.z; o.w += a.w + b.w;
  *(float4*)(out + (i << 2)) = o;
}

extern "C" void kernel_launch(void* const* d_in, const int* in_sizes, int n_in,
                              void* d_out, int out_size, void* d_ws, size_t ws_size,
                              hipStream_t stream) {
  const float* x    = (const float*)d_in[0];
  const float* ln1g = (const float*)d_in[1];
  const float* ln1b = (const float*)d_in[2];
  const float* Wqkv = (const float*)d_in[3];
  const float* Wo   = (const float*)d_in[4];
  const float* ln2g = (const float*)d_in[5];
  const float* ln2b = (const float*)d_in[6];
  const float* Wg   = (const float*)d_in[7];
  const float* W1   = (const float*)d_in[8];
  const float* W2   = (const float*)d_in[9];
  float* out = (float*)d_out;
  char* ws = (char*)d_ws;

  size_t off = 0;
  auto alloc = [&](size_t b) { size_t o = off; off += (b + 255) & ~size_t(255); return o; };
  u16* WqkvTh = (u16*)(ws + alloc(3072ull * 1024 * 2));
  u16* WqkvTl = (u16*)(ws + alloc(3072ull * 1024 * 2));
  u16* WoTh   = (u16*)(ws + alloc(1024ull * 1024 * 2));
  u16* WoTl   = (u16*)(ws + alloc(1024ull * 1024 * 2));
  u16* W1T    = (u16*)(ws + alloc(8ull * 4096 * 1024 * 2));
  u16* W2T    = (u16*)(ws + alloc(8ull * 1024 * 4096 * 2));
  u16* hh     = (u16*)(ws + alloc(4096ull * 1024 * 2));
  u16* hl     = (u16*)(ws + alloc(4096ull * 1024 * 2));
  float* qkv  = (float*)(ws + alloc(4096ull * 3072 * 4));
  u16* atth   = (u16*)(ws + alloc(4096ull * 1024 * 2));
  u16* attl   = (u16*)(ws + alloc(4096ull * 1024 * 2));
  u16* moein  = (u16*)(ws + alloc(4096ull * 1024 * 2));
  u16* act    = (u16*)(ws + alloc(8192ull * 4096 * 2));
  float* WgT  = (float*)(ws + alloc(8ull * 1024 * 4));
  float* ypart = qkv;  // alias: qkv (50.3MB) dead after attention; ypart needs 33.6MB
  // K/V f16 planes alias into act (dead until FFN1): 4 planes x 8MB = 32MB < 67MB
  u16* Kh  = act;
  u16* Kl  = act + 4194304;
  u16* Vth = act + 2 * 4194304;
  u16* Vtl = act + 3 * 4194304;
  int* tok_e  = (int*)(ws + alloc(8192 * 4));
  float* tok_w = (float*)(ws + alloc(8192 * 4));
  int* cursor = (int*)(ws + alloc(64));
  int* lists  = (int*)(ws + alloc(8192 * 4));
  float* slotw = (float*)(ws + alloc(8192 * 4));
  int* tile_e = (int*)(ws + alloc(MAXT * 4));
  int* tile_b = (int*)(ws + alloc(MAXT * 4));
  int* tile_c = (int*)(ws + alloc(MAXT * 4));
  int* tile2_e = (int*)(ws + alloc(MAXT2 * 4));
  int* tile2_b = (int*)(ws + alloc(MAXT2 * 4));
  int* tile2_c = (int*)(ws + alloc(MAXT2 * 4));
  (void)in_sizes; (void)n_in; (void)out_size; (void)ws_size;

  dim3 blk(256), blk512(512);
  // weight transpose+convert (B^T layout for all GEMMs) + WgT for gate
  transpose_kernel<0><<<dim3(96, 32, 1), blk, 0, stream>>>(Wqkv, WqkvTh, WqkvTl, 1024, 3072);
  transpose_kernel<0><<<dim3(32, 32, 1), blk, 0, stream>>>(Wo, WoTh, WoTl, 1024, 1024);
  transpose_kernel<1><<<dim3(128, 32, 8), blk, 0, stream>>>(W1, W1T, nullptr, 1024, 4096);
  transpose_kernel<1><<<dim3(32, 128, 8), blk, 0, stream>>>(W2, W2T, nullptr, 4096, 1024);
  wg_transpose<<<dim3(32), blk, 0, stream>>>(Wg, WgT);
  // LN1 -> h (f16 hi/lo)
  ln_kernel<<<dim3(4096), blk, 0, stream>>>(x, ln1g, ln1b, hh, hl);
  // QKV = h @ Wqkv (split-f16 x3, 512 thr) -> f32
  gemm_kernel<0><<<dim3(24, 32), blk512, 0, stream>>>(hh, hl, WqkvTh, WqkvTl, 1024, 3072, 0,
                                                      nullptr, nullptr, nullptr, nullptr,
                                                      qkv, nullptr, nullptr, nullptr);
  // K/V pre-convert to split-f16 planes
  kv_prep<<<dim3(16, 16, 4), blk, 0, stream>>>(qkv, Kh, Kl, Vth, Vtl);
  // flash attention (balanced causal pairing: each block does 17 tile-steps)
  attn_kernel<<<dim3(8, 16, 4), blk, 0, stream>>>(qkv, Kh, Kl, Vth, Vtl, atth, attl);
  // x_resid = x + attn @ Wo (split-f16 x3, TN=64, 512 thr) -> d_out
  gemm_kernel<1><<<dim3(16, 32), blk512, 0, stream>>>(atth, attl, WoTh, WoTl, 1024, 1024, 0,
                                                      nullptr, nullptr, nullptr, nullptr,
                                                      out, nullptr, x, nullptr);
  // routing (f32, WgT coalesced, no atomics) + fused LN2 -> moein
  gate_kernel<<<dim3(1024), blk, 0, stream>>>(out, ln2g, ln2b, WgT, tok_e, tok_w, moein);
  // plan: histogram tok_e + both tile tables + cursor init (single block)
  plan_kernel<<<dim3(1), blk, 0, stream>>>(tok_e, cursor, tile_e, tile_b, tile_c,
                                           tile2_e, tile2_b, tile2_c);
  scatter_kernel<<<dim3(16), blk, 0, stream>>>(tok_e, tok_w, cursor, lists, slotw);
  // FFN1: gather tokens, gelu(h @ W1[e]) -> act bf16 (BM=128 TN=128, XCD-chunked, grid 2304)
  gemm_kernel<2><<<dim3(8 * 9 * 32), blk512, 0, stream>>>(moein, nullptr, W1T, nullptr, 1024, 4096, 4096,
                                                          lists, tile_e, tile_b, tile_c,
                                                          nullptr, act, nullptr, nullptr);
  // FFN2: act @ W2[e] * gate -> ypart scatter (BM=64 TN=128, 64-row tiles, grid 1088)
  gemm_kernel<3><<<dim3(8 * 17 * 8), blk512, 0, stream>>>(act, nullptr, W2T, nullptr, 4096, 1024, 1024,
                                                          lists, tile2_e, tile2_b, tile2_c,
                                                          ypart, nullptr, nullptr, slotw);
  // out = x_resid + y0 + y1
  combine_kernel<<<dim3(4096), blk, 0, stream>>>(out, ypart);
}

// Round 13
// 547.433 us; speedup vs baseline: 1.0596x; 1.0596x over previous
//
#include <hip/hip_runtime.h>

// B=4 S=1024 D=1024 H=16 HD=64 E=8 TOPK=2 F=4096 ; tokens N=4096
typedef unsigned short u16;
typedef _Float16 f16x8 __attribute__((ext_vector_type(8)));
typedef __bf16   bf16x8 __attribute__((ext_vector_type(8)));
typedef float    f32x4 __attribute__((ext_vector_type(4)));

struct __align__(8) U16x4 { u16 v[4]; };

#define MAXT 72

__device__ __forceinline__ u16 f2b(float f) {            // f32 -> bf16 RNE bits
  unsigned u = __builtin_bit_cast(unsigned, f);
  return (u16)((u + 0x7FFFu + ((u >> 16) & 1u)) >> 16);
}
__device__ __forceinline__ u16 f2h(float f) { return __builtin_bit_cast(u16, (_Float16)f); }
__device__ __forceinline__ u16 f2h_lo(float f) {
  _Float16 h = (_Float16)f;
  return __builtin_bit_cast(u16, (_Float16)(f - (float)h));
}
__device__ __forceinline__ void llds16(const void* g, void* l) {
  __builtin_amdgcn_global_load_lds((const __attribute__((address_space(1))) unsigned int*)g,
                                   (__attribute__((address_space(3))) unsigned int*)l, 16, 0, 0);
}
__device__ __forceinline__ f32x4 mmf(f16x8 a, f16x8 b, f32x4 c) {
  return __builtin_amdgcn_mfma_f32_16x16x32_f16(a, b, c, 0, 0, 0);
}
__device__ __forceinline__ f32x4 mmb(bf16x8 a, bf16x8 b, f32x4 c) {
  return __builtin_amdgcn_mfma_f32_16x16x32_bf16(a, b, c, 0, 0, 0);
}

// ---------------- transpose + convert: src [R,C] f32 -> dst [C,R] f16(hi/lo) or bf16 ----
template<int OUT> // 0: f16 split pair, 1: bf16 single
__global__ __launch_bounds__(256) void transpose_kernel(const float* __restrict__ src,
                                                        u16* __restrict__ d0, u16* __restrict__ d1,
                                                        int R, int C) {
  __shared__ float t[32][33];
  long zo = (long)blockIdx.z * R * C;
  int r0 = blockIdx.y << 5, c0 = blockIdx.x << 5;
  int tid = threadIdx.x;
  {
    int r = tid >> 3, c = (tid & 7) << 2;
    float4 v = *(const float4*)(src + zo + (long)(r0 + r) * C + c0 + c);
    t[r][c] = v.x; t[r][c + 1] = v.y; t[r][c + 2] = v.z; t[r][c + 3] = v.w;
  }
  __syncthreads();
  int c = tid >> 3, rg = (tid & 7) << 2;
  long o = zo + (long)(c0 + c) * R + r0 + rg;
  U16x4 a, b2;
#pragma unroll
  for (int i = 0; i < 4; i++) {
    float f = t[rg + i][c];
    if (OUT == 0) { a.v[i] = f2h(f); b2.v[i] = f2h_lo(f); }
    else a.v[i] = f2b(f);
  }
  *(U16x4*)(d0 + o) = a;
  if (OUT == 0) *(U16x4*)(d1 + o) = b2;
}

// ---------------- Wg [1024,8] -> WgT [8,1024] (tiny, for coalesced gate loads) ---------
__global__ __launch_bounds__(256) void wg_transpose(const float* __restrict__ Wg,
                                                    float* __restrict__ WgT) {
  int idx = blockIdx.x * 256 + threadIdx.x;   // 8192 elements
  int d = idx >> 3, e = idx & 7;
  WgT[e * 1024 + d] = Wg[idx];
}

// ---------------- LayerNorm row kernel (LN1 only; LN2 fused into gate) ----------------
__global__ __launch_bounds__(256) void ln_kernel(const float* __restrict__ x, const float* __restrict__ g,
                                                 const float* __restrict__ bt,
                                                 u16* __restrict__ d0, u16* __restrict__ d1) {
  long row = blockIdx.x;
  int tid = threadIdx.x;
  const float4 v = *(const float4*)(x + (row << 10) + (tid << 2));
  float s = v.x + v.y + v.z + v.w;
  float q = v.x * v.x + v.y * v.y + v.z * v.z + v.w * v.w;
#pragma unroll
  for (int m = 1; m < 64; m <<= 1) { s += __shfl_xor(s, m); q += __shfl_xor(q, m); }
  __shared__ float rs[4], rq[4];
  if ((tid & 63) == 0) { rs[tid >> 6] = s; rq[tid >> 6] = q; }
  __syncthreads();
  s = rs[0] + rs[1] + rs[2] + rs[3];
  q = rq[0] + rq[1] + rq[2] + rq[3];
  float mu = s * (1.f / 1024.f);
  float inv = 1.f / sqrtf(q * (1.f / 1024.f) - mu * mu + 1e-5f);
  float4 gg = *(const float4*)(g + (tid << 2));
  float4 bb = *(const float4*)(bt + (tid << 2));
  float o0 = (v.x - mu) * inv * gg.x + bb.x;
  float o1 = (v.y - mu) * inv * gg.y + bb.y;
  float o2 = (v.z - mu) * inv * gg.z + bb.z;
  float o3 = (v.w - mu) * inv * gg.w + bb.w;
  long o = (row << 10) + (tid << 2);
  U16x4 a, b2;
  a.v[0] = f2h(o0); a.v[1] = f2h(o1); a.v[2] = f2h(o2); a.v[3] = f2h(o3);
  b2.v[0] = f2h_lo(o0); b2.v[1] = f2h_lo(o1); b2.v[2] = f2h_lo(o2); b2.v[3] = f2h_lo(o3);
  *(U16x4*)(d0 + o) = a; *(U16x4*)(d1 + o) = b2;
}

// ------- unified tiled GEMM, 128xTN xK BK=64, A[M,K] x Bt[N,K], 512 thr / 8 waves -------
// Wave grid 2x4: wave covers 64 x (TN/4) of the tile (acc[4][NF], NF = TN/64).
// MODE 0: split f16 x3 -> f32 out (QKV), TN=128, single-buffered.
// MODE 1: split f16 x3 -> f32 + resid (Wo), TN=64, single-buffered.
// MODE 2: bf16, A gathered via lists -> gelu -> bf16 (FFN1), TN=128, XCD-chunked, 32KB.
// MODE 3: bf16 COUNTED-VMCNT 2-DEEP PIPELINE (T4), A direct grouped -> scatter (FFN2),
//         TN=128, XCD-chunked, 64KB dbuf. vmcnt never drains to 0 in the main loop.
template<int MODE>
__global__ __launch_bounds__(512, 1) void gemm_kernel(
    const u16* __restrict__ Ah, const u16* __restrict__ Al,
    const u16* __restrict__ Bh, const u16* __restrict__ Bl,
    int K, int ldc, int Nexp,
    const int* __restrict__ lists, const int* __restrict__ tile_e,
    const int* __restrict__ tile_b, const int* __restrict__ tile_c,
    float* __restrict__ outf, u16* __restrict__ outb,
    const float* __restrict__ resid, const float* __restrict__ slotw) {
  constexpr bool SPLIT = (MODE < 2);
  constexpr int TN = (MODE == 1) ? 64 : 128;   // tile N
  constexpr int NF = TN >> 6;                  // n-frags per wave (2 or 1)
  constexpr int NB = TN >> 6;                  // B staging chunks per thread (2 or 1)
  constexpr int SMEM = (MODE == 2) ? 32768 : 65536;
  __shared__ __align__(16) char smem[SMEM];
  // SPLIT: Ah=+0, Bh=+16K, Al=+32K, Bl=+48K. MODE2: A=+0, B=+16K.
  // MODE3: buf0 {A=+0,B=+16K}, buf1 {A=+32K,B=+48K}.
  const int tid = threadIdx.x, w = tid >> 6, l = tid & 63;
  int n0;
  int grbase = 0, rowsv = 128;
  long m0 = 0;
  if (MODE >= 2) {
    // Chunked XCD swizzle: XCD c owns 9 consecutive y-tiles (A-panel sharers colocate
    // on one L2; an expert's tiles stay mostly within one XCD for W reuse).
    int lin = blockIdx.x;
    int c = lin & 7, k = lin >> 3;
    int ty = c * 9 + (k % 9);      // tile index [0,72)
    int tx = k / 9;                // n-tile
    n0 = tx * TN;
    int e = tile_e[ty];
    if (e < 0) return;
    grbase = tile_b[ty];
    rowsv = tile_c[ty];
    Bh += (long)e * Nexp * K;
  } else {
    n0 = blockIdx.x * TN;
    m0 = (long)blockIdx.y << 7;
  }

  const u16 *as0[2], *as1[2], *bs0[2], *bs1[2];
  int dstA[2], dstB[2];
#pragma unroll
  for (int i = 0; i < 2; i++) {        // A: 1024 chunks of 16B over 512 threads
    int chunk = i * 512 + tid;
    int row = chunk >> 3, c16 = chunk & 7;
    int scol = (c16 << 4) ^ ((row & 7) << 4);   // pre-swizzled source byte col
    dstA[i] = chunk << 4;
    long ar;
    if (MODE == 2) {
      int vlu = lists[(row < rowsv) ? (grbase + row) : grbase];
      ar = (long)(vlu >> 1);
    } else if (MODE == 3) {
      ar = grbase + ((row < rowsv) ? row : 0);
    } else {
      ar = m0 + row;
    }
    long ao = ar * (long)K + (scol >> 1);
    as0[i] = Ah + ao;
    if (SPLIT) as1[i] = Al + ao;
  }
#pragma unroll
  for (int i = 0; i < NB; i++) {       // B: TN*8 chunks of 16B over 512 threads
    int chunk = i * 512 + tid;
    int row = chunk >> 3, c16 = chunk & 7;
    int scol = (c16 << 4) ^ ((row & 7) << 4);
    dstB[i] = chunk << 4;
    long bo = (long)(n0 + row) * K + (scol >> 1);
    bs0[i] = Bh + bo;
    if (SPLIT) bs1[i] = Bl + bo;
  }

  f32x4 acc[4][NF];
#pragma unroll
  for (int i = 0; i < 4; i++)
#pragma unroll
    for (int j = 0; j < NF; j++) acc[i][j] = (f32x4){0.f, 0.f, 0.f, 0.f};

  const int wr = (w >> 2) << 6;            // wave-row: 2 rows of 64
  const int wc = (w & 3) * (TN / 4);       // wave-col: 4 cols of TN/4
  const int nkt = K >> 6;

  if constexpr (MODE == 3) {
    // prologue: stage tiles 0 and 1 (4 llds16 each per thread; issue order pinned)
#pragma unroll
    for (int i = 0; i < 2; i++) llds16(as0[i], smem + dstA[i]);
#pragma unroll
    for (int i = 0; i < 2; i++) llds16(bs0[i], smem + 16384 + dstB[i]);
    asm volatile("" ::: "memory");   // pin issue order: tile-0 loads before tile-1
#pragma unroll
    for (int i = 0; i < 2; i++) llds16(as0[i] + 64, smem + 32768 + dstA[i]);
#pragma unroll
    for (int i = 0; i < 2; i++) llds16(bs0[i] + 64, smem + 49152 + dstB[i]);
    for (int kt = 0; kt < nkt; ++kt) {
      const int cur = kt & 1;
      if (kt + 1 < nkt) asm volatile("s_waitcnt vmcnt(4)" ::: "memory");  // own tile-kt loads done
      else              asm volatile("s_waitcnt vmcnt(0)" ::: "memory");
      asm volatile("s_barrier" ::: "memory");   // all waves' tile-kt loads in LDS
      const char* pA = (const char*)smem + (cur << 15);
      const char* pB = pA + 16384;
#pragma unroll
      for (int kc = 0; kc < 2; kc++) {
        const int kby = (kc << 6) + ((l >> 4) << 4);
        bf16x8 a0[4], b0[NF];
#pragma unroll
        for (int mf = 0; mf < 4; mf++) {
          int row = wr + (mf << 4) + (l & 15);
          a0[mf] = *(const bf16x8*)(pA + (row << 7) + (kby ^ ((row & 7) << 4)));
        }
#pragma unroll
        for (int nf = 0; nf < NF; nf++) {
          int row = wc + (nf << 4) + (l & 15);
          b0[nf] = *(const bf16x8*)(pB + (row << 7) + (kby ^ ((row & 7) << 4)));
        }
#pragma unroll
        for (int mf = 0; mf < 4; mf++)
#pragma unroll
          for (int nf = 0; nf < NF; nf++) acc[mf][nf] = mmb(a0[mf], b0[nf], acc[mf][nf]);
      }
      asm volatile("s_barrier" ::: "memory");   // all waves done reading buf[cur]
      if (kt + 2 < nkt) {
        char* qa = (char*)smem + (cur << 15);
#pragma unroll
        for (int i = 0; i < 2; i++) llds16(as0[i] + ((kt + 2) << 6), qa + dstA[i]);
#pragma unroll
        for (int i = 0; i < 2; i++) llds16(bs0[i] + ((kt + 2) << 6), qa + 16384 + dstB[i]);
      }
    }
  } else {
    char* pAh = smem;
    char* pBh = smem + 16384;
    char* pAl = smem + 32768;   // SPLIT only
    char* pBl = smem + 49152;   // SPLIT only
    for (int kt = 0; kt < nkt; ++kt) {
      if (kt) __syncthreads();
#pragma unroll
      for (int i = 0; i < 2; i++) {
        llds16(as0[i] + (kt << 6), pAh + dstA[i]);
        if (SPLIT) llds16(as1[i] + (kt << 6), pAl + dstA[i]);
      }
#pragma unroll
      for (int i = 0; i < NB; i++) {
        llds16(bs0[i] + (kt << 6), pBh + dstB[i]);
        if (SPLIT) llds16(bs1[i] + (kt << 6), pBl + dstB[i]);
      }
      __syncthreads();
#pragma unroll
      for (int kc = 0; kc < 2; kc++) {
        const int kby = (kc << 6) + ((l >> 4) << 4);
        int aoff[4], boff[NF];
#pragma unroll
        for (int mf = 0; mf < 4; mf++) { int row = wr + (mf << 4) + (l & 15); aoff[mf] = (row << 7) + (kby ^ ((row & 7) << 4)); }
#pragma unroll
        for (int nf = 0; nf < NF; nf++) { int row = wc + (nf << 4) + (l & 15); boff[nf] = (row << 7) + (kby ^ ((row & 7) << 4)); }
        if (SPLIT) {
          f16x8 a0[4], a1[4], b0[NF], b1[NF];
#pragma unroll
          for (int mf = 0; mf < 4; mf++) {
            a0[mf] = *(const f16x8*)(pAh + aoff[mf]);
            a1[mf] = *(const f16x8*)(pAl + aoff[mf]);
          }
#pragma unroll
          for (int nf = 0; nf < NF; nf++) {
            b0[nf] = *(const f16x8*)(pBh + boff[nf]);
            b1[nf] = *(const f16x8*)(pBl + boff[nf]);
          }
#pragma unroll
          for (int mf = 0; mf < 4; mf++)
#pragma unroll
            for (int nf = 0; nf < NF; nf++) {
              acc[mf][nf] = mmf(a0[mf], b0[nf], acc[mf][nf]);
              acc[mf][nf] = mmf(a0[mf], b1[nf], acc[mf][nf]);
              acc[mf][nf] = mmf(a1[mf], b0[nf], acc[mf][nf]);
            }
        } else {
          bf16x8 a0[4], b0[NF];
#pragma unroll
          for (int mf = 0; mf < 4; mf++) a0[mf] = *(const bf16x8*)(pAh + aoff[mf]);
#pragma unroll
          for (int nf = 0; nf < NF; nf++) b0[nf] = *(const bf16x8*)(pBh + boff[nf]);
#pragma unroll
          for (int mf = 0; mf < 4; mf++)
#pragma unroll
            for (int nf = 0; nf < NF; nf++) acc[mf][nf] = mmb(a0[mf], b0[nf], acc[mf][nf]);
        }
      }
    }
  }

  // epilogue: C/D layout col = lane&15, row = (lane>>4)*4 + reg
#pragma unroll
  for (int mf = 0; mf < 4; mf++) {
#pragma unroll
    for (int r = 0; r < 4; r++) {
      const int lrow = wr + (mf << 4) + ((l >> 4) << 2) + r;
      if (MODE >= 2 && lrow >= rowsv) continue;
      float gw = 0.f; long orow = 0;
      if (MODE == 3) { int gr = grbase + lrow; orow = (long)lists[gr] * ldc; gw = slotw[gr]; }
#pragma unroll
      for (int nf = 0; nf < NF; nf++) {
        const int col = n0 + wc + (nf << 4) + (l & 15);
        float v = acc[mf][nf][r];
        if (MODE == 0) {
          outf[(m0 + lrow) * (long)ldc + col] = v;
        } else if (MODE == 1) {
          long ix = (m0 + lrow) * (long)ldc + col;
          outf[ix] = v + resid[ix];
        } else if (MODE == 2) {
          // gelu(v) = v * sigmoid(1.5957691 v + 0.0713549 v^3)  (exact tanh-form identity)
          float t = v * (1.59576912f + 0.07135539f * v * v);
          float u = v * __builtin_amdgcn_rcpf(1.f + __expf(-t));
          outb[(long)(grbase + lrow) * ldc + col] = f2b(u);
        } else {
          outf[orow + col] = v * gw;
        }
      }
    }
  }
}

// ---------------- K/V pre-convert: per (b,h) planes Kh/Kl [1024][64], Vth/Vtl [64][1024] ----
__global__ __launch_bounds__(256) void kv_prep(const float* __restrict__ qkv,
                                               u16* __restrict__ Kh, u16* __restrict__ Kl,
                                               u16* __restrict__ Vth, u16* __restrict__ Vtl) {
  __shared__ float t[64][65];
  const int tid = threadIdx.x;
  const int kb = blockIdx.x, h = blockIdx.y, b = blockIdx.z;
  const long bb = ((long)b) << 10;
  const int hoff = h << 6;
  const long head = ((long)(b * 16 + h)) << 16;   // 65536 elems per head-plane
  {
    int rr = tid >> 4, c = (tid & 15) << 2;
#pragma unroll
    for (int p = 0; p < 4; p++) {
      int r = rr + p * 16;
      const float* base = qkv + (bb + kb * 64 + r) * 3072 + hoff + c;
      float4 u = *(const float4*)(base + 1024);
      U16x4 a, lo;
      a.v[0] = f2h(u.x); a.v[1] = f2h(u.y); a.v[2] = f2h(u.z); a.v[3] = f2h(u.w);
      lo.v[0] = f2h_lo(u.x); lo.v[1] = f2h_lo(u.y); lo.v[2] = f2h_lo(u.z); lo.v[3] = f2h_lo(u.w);
      long o = head + (long)(kb * 64 + r) * 64 + c;
      *(U16x4*)(Kh + o) = a; *(U16x4*)(Kl + o) = lo;
      float4 v = *(const float4*)(base + 2048);
      t[r][c] = v.x; t[r][c + 1] = v.y; t[r][c + 2] = v.z; t[r][c + 3] = v.w;
    }
  }
  __syncthreads();
  {
    int hd = tid >> 2, k4 = (tid & 3) << 4;
#pragma unroll
    for (int q = 0; q < 4; q++) {
      U16x4 a, lo;
#pragma unroll
      for (int j = 0; j < 4; j++) {
        float f = t[k4 + q * 4 + j][hd];
        a.v[j] = f2h(f); lo.v[j] = f2h_lo(f);
      }
      long o = head + (long)hd * 1024 + kb * 64 + k4 + q * 4;
      *(U16x4*)(Vth + o) = a; *(U16x4*)(Vtl + o) = lo;
    }
  }
}

// ---------------- flash attention v2: prepped K/V planes, llds staging, balanced pairing ----
__global__ __launch_bounds__(256, 1) void attn_kernel(const float* __restrict__ qkv,
                                                      const u16* __restrict__ Kh, const u16* __restrict__ Kl,
                                                      const u16* __restrict__ Vth, const u16* __restrict__ Vtl,
                                                      u16* __restrict__ oh, u16* __restrict__ ol) {
  __shared__ u16 kh[4096], kl[4096];       // K tile [64 key][64 hd], swizzled
  __shared__ u16 vh[4096], vl[4096];       // V^T tile [64 hd][64 key], swizzled
  __shared__ u16 ph[4][1024], pl[4][1024]; // per-wave P [16 m][64 k]
  const int tid = threadIdx.x, w = tid >> 6, l = tid & 63;
  const int qbi = blockIdx.x, hh_ = blockIdx.y, b = blockIdx.z;
  const long bb = ((long)b) << 10;
  const int hoff = hh_ << 6;
  const long head = ((long)(b * 16 + hh_)) << 16;

  // staging descriptors (2 chunks of 16B per thread per plane)
  const u16 *ks0[2], *ks1[2], *vs0[2], *vs1[2];
  int db[2];
#pragma unroll
  for (int i = 0; i < 2; i++) {
    int chunk = i * 256 + tid;
    int row = chunk >> 3, c16 = chunk & 7;
    int sc = ((c16 << 4) ^ ((row & 7) << 4)) >> 1;
    db[i] = chunk << 4;
    ks0[i] = Kh + head + row * 64 + sc;
    ks1[i] = Kl + head + row * 64 + sc;
    vs0[i] = Vth + head + (long)row * 1024 + sc;
    vs1[i] = Vtl + head + (long)row * 1024 + sc;
  }

  for (int pass = 0; pass < 2; ++pass) {
    const int qb = (pass ? qbi : (15 - qbi)) << 6;   // long pass first; total 17 tiles/block
    // load Q fragments (split f16)
    f16x8 q0[2], q1[2];
    {
      const long qrow = bb + qb + (w << 4) + (l & 15);
      const float* qp = qkv + qrow * 3072 + hoff + ((l >> 4) << 3);
#pragma unroll
      for (int kc = 0; kc < 2; kc++) {
        float4 u0 = *(const float4*)(qp + (kc << 5));
        float4 u1 = *(const float4*)(qp + (kc << 5) + 4);
        float vv[8] = {u0.x, u0.y, u0.z, u0.w, u1.x, u1.y, u1.z, u1.w};
#pragma unroll
        for (int j = 0; j < 8; j++) {
          _Float16 hi = (_Float16)vv[j];
          q0[kc][j] = hi;
          q1[kc][j] = (_Float16)(vv[j] - (float)hi);
        }
      }
    }

    f32x4 o[4];
#pragma unroll
    for (int nf = 0; nf < 4; nf++) o[nf] = (f32x4){0.f, 0.f, 0.f, 0.f};
    float mr[4] = {-1e30f, -1e30f, -1e30f, -1e30f};
    float lr[4] = {0.f, 0.f, 0.f, 0.f};
    const int ktm = qb >> 6;

    for (int kt = 0; kt <= ktm; ++kt) {
      __syncthreads();
#pragma unroll
      for (int i = 0; i < 2; i++) {
        llds16(ks0[i] + (kt << 12), (char*)kh + db[i]);
        llds16(ks1[i] + (kt << 12), (char*)kl + db[i]);
        llds16(vs0[i] + (kt << 6), (char*)vh + db[i]);
        llds16(vs1[i] + (kt << 6), (char*)vl + db[i]);
      }
      __syncthreads();

      // QK^T (split x3)
      f32x4 s[4];
#pragma unroll
      for (int nf = 0; nf < 4; nf++) s[nf] = (f32x4){0.f, 0.f, 0.f, 0.f};
#pragma unroll
      for (int kc = 0; kc < 2; kc++) {
        const int kby = (kc << 6) + ((l >> 4) << 4);
#pragma unroll
        for (int nf = 0; nf < 4; nf++) {
          int row = (nf << 4) + (l & 15);
          int off = (row << 7) + (kby ^ ((row & 7) << 4));
          f16x8 k0 = *(const f16x8*)((const char*)kh + off);
          f16x8 k1 = *(const f16x8*)((const char*)kl + off);
          s[nf] = mmf(q0[kc], k0, s[nf]);
          s[nf] = mmf(q0[kc], k1, s[nf]);
          s[nf] = mmf(q1[kc], k0, s[nf]);
        }
      }
      const bool lastt = (kt == ktm);
#pragma unroll
      for (int nf = 0; nf < 4; nf++)
#pragma unroll
        for (int r = 0; r < 4; r++) {
          float sc = s[nf][r] * 0.125f;
          if (lastt) {
            int keyg = (kt << 6) + (nf << 4) + (l & 15);
            int qg = qb + (w << 4) + ((l >> 4) << 2) + r;
            if (keyg > qg) sc = -1e30f;
          }
          s[nf][r] = sc;
        }
      float alpha[4];
#pragma unroll
      for (int r = 0; r < 4; r++) {
        float mx = fmaxf(fmaxf(s[0][r], s[1][r]), fmaxf(s[2][r], s[3][r]));
        mx = fmaxf(mx, __shfl_xor(mx, 1));
        mx = fmaxf(mx, __shfl_xor(mx, 2));
        mx = fmaxf(mx, __shfl_xor(mx, 4));
        mx = fmaxf(mx, __shfl_xor(mx, 8));
        float mn = fmaxf(mr[r], mx);
        float su = 0.f;
#pragma unroll
        for (int nf = 0; nf < 4; nf++) { float pv = __expf(s[nf][r] - mn); s[nf][r] = pv; su += pv; }
        su += __shfl_xor(su, 1); su += __shfl_xor(su, 2);
        su += __shfl_xor(su, 4); su += __shfl_xor(su, 8);
        alpha[r] = __expf(mr[r] - mn);
        lr[r] = lr[r] * alpha[r] + su;
        mr[r] = mn;
      }
#pragma unroll
      for (int nf = 0; nf < 4; nf++)
#pragma unroll
        for (int r = 0; r < 4; r++) o[nf][r] *= alpha[r];
      // write P (hi/lo) to per-wave LDS
#pragma unroll
      for (int nf = 0; nf < 4; nf++)
#pragma unroll
        for (int r = 0; r < 4; r++) {
          int m = ((l >> 4) << 2) + r, k = (nf << 4) + (l & 15);
          int off = (m << 7) + ((k << 1) ^ ((m & 7) << 4));
          float pv = s[nf][r];
          _Float16 hi = (_Float16)pv;
          *(u16*)((char*)&ph[w][0] + off) = __builtin_bit_cast(u16, hi);
          *(u16*)((char*)&pl[w][0] + off) = __builtin_bit_cast(u16, (_Float16)(pv - (float)hi));
        }
      // PV (split x3)
#pragma unroll
      for (int kc = 0; kc < 2; kc++) {
        const int kby = (kc << 6) + ((l >> 4) << 4);
        const int mm = l & 15;
        int poff = (mm << 7) + (kby ^ ((mm & 7) << 4));
        f16x8 p0 = *(const f16x8*)((const char*)&ph[w][0] + poff);
        f16x8 p1 = *(const f16x8*)((const char*)&pl[w][0] + poff);
#pragma unroll
        for (int nf = 0; nf < 4; nf++) {
          int row = (nf << 4) + (l & 15);
          int off = (row << 7) + (kby ^ ((row & 7) << 4));
          f16x8 v0 = *(const f16x8*)((const char*)vh + off);
          f16x8 v1 = *(const f16x8*)((const char*)vl + off);
          o[nf] = mmf(p0, v0, o[nf]);
          o[nf] = mmf(p0, v1, o[nf]);
          o[nf] = mmf(p1, v0, o[nf]);
        }
      }
    }
    // store O split to f16 planes
#pragma unroll
    for (int nf = 0; nf < 4; nf++)
#pragma unroll
      for (int r = 0; r < 4; r++) {
        int lrow = (w << 4) + ((l >> 4) << 2) + r;
        float v = o[nf][r] / lr[r];
        long ix = (bb + qb + lrow) * 1024 + hoff + (nf << 4) + (l & 15);
        _Float16 hi = (_Float16)v;
        oh[ix] = __builtin_bit_cast(u16, hi);
        ol[ix] = __builtin_bit_cast(u16, (_Float16)(v - (float)hi));
      }
  }
}

// ------- gating v2: f32 LN + logits (WgT coalesced) + top2, fused LN2 out, NO atomics ----
__global__ __launch_bounds__(256) void gate_kernel(const float* __restrict__ xr, const float* __restrict__ g,
                                                   const float* __restrict__ b, const float* __restrict__ WgT,
                                                   int* __restrict__ tok_e, float* __restrict__ tok_w,
                                                   u16* __restrict__ moe) {
  int w = threadIdx.x >> 6, l = threadIdx.x & 63;
  long t = (long)blockIdx.x * 4 + w;
  const float* row = xr + (t << 10);
  float4 xv[4]; float s = 0.f, q = 0.f;
#pragma unroll
  for (int i = 0; i < 4; i++) {
    float4 v = *(const float4*)(row + (i << 8) + (l << 2));
    xv[i] = v;
    s += v.x + v.y + v.z + v.w;
    q += v.x * v.x + v.y * v.y + v.z * v.z + v.w * v.w;
  }
#pragma unroll
  for (int m = 1; m < 64; m <<= 1) { s += __shfl_xor(s, m); q += __shfl_xor(q, m); }
  float mu = s * (1.f / 1024.f);
  float inv = 1.f / sqrtf(q * (1.f / 1024.f) - mu * mu + 1e-5f);
  float acc[8] = {0.f, 0.f, 0.f, 0.f, 0.f, 0.f, 0.f, 0.f};
#pragma unroll
  for (int i = 0; i < 4; i++) {
    int d0 = (i << 8) + (l << 2);
    float4 gg = *(const float4*)(g + d0);
    float4 bb = *(const float4*)(b + d0);
    float x0 = (xv[i].x - mu) * inv * gg.x + bb.x;
    float x1 = (xv[i].y - mu) * inv * gg.y + bb.y;
    float x2 = (xv[i].z - mu) * inv * gg.z + bb.z;
    float x3 = (xv[i].w - mu) * inv * gg.w + bb.w;
    U16x4 st;
    st.v[0] = f2b(x0); st.v[1] = f2b(x1); st.v[2] = f2b(x2); st.v[3] = f2b(x3);
    *(U16x4*)(moe + (t << 10) + d0) = st;
#pragma unroll
    for (int e = 0; e < 8; e++) {
      float4 wq = *(const float4*)(WgT + (e << 10) + d0);
      acc[e] += x0 * wq.x + x1 * wq.y + x2 * wq.z + x3 * wq.w;
    }
  }
#pragma unroll
  for (int e = 0; e < 8; e++)
#pragma unroll
    for (int m = 1; m < 64; m <<= 1) acc[e] += __shfl_xor(acc[e], m);
  if (l == 0) {
    int e0 = 0; float v0 = acc[0];
#pragma unroll
    for (int e = 1; e < 8; e++) if (acc[e] > v0) { v0 = acc[e]; e0 = e; }
    int e1 = (e0 == 0) ? 1 : 0; float v1 = acc[e1];
#pragma unroll
    for (int e = 0; e < 8; e++) if (e != e0 && acc[e] > v1) { v1 = acc[e]; e1 = e; }
    float w0 = 1.f / (1.f + __expf(v1 - v0));
    tok_e[t * 2] = e0; tok_e[t * 2 + 1] = e1;
    tok_w[t * 2] = w0; tok_w[t * 2 + 1] = 1.f - w0;
  }
}

// ------- plan v2: 256-thread histogram of tok_e (named counters + shuffle reduce) -------
__global__ __launch_bounds__(256) void plan_kernel(const int* __restrict__ tok_e, int* __restrict__ cursor,
                                                   int* __restrict__ tile_e, int* __restrict__ tile_b,
                                                   int* __restrict__ tile_c) {
  __shared__ int wc[4][8];
  int tid = threadIdx.x, w = tid >> 6, l = tid & 63;
  int c0 = 0, c1 = 0, c2 = 0, c3 = 0, c4 = 0, c5 = 0, c6 = 0, c7 = 0;
  for (int k = 0; k < 32; k++) {
    int v = tok_e[(w << 11) + (k << 6) + l];
    c0 += (v == 0); c1 += (v == 1); c2 += (v == 2); c3 += (v == 3);
    c4 += (v == 4); c5 += (v == 5); c6 += (v == 6); c7 += (v == 7);
  }
#pragma unroll
  for (int m = 1; m < 64; m <<= 1) {
    c0 += __shfl_xor(c0, m); c1 += __shfl_xor(c1, m); c2 += __shfl_xor(c2, m); c3 += __shfl_xor(c3, m);
    c4 += __shfl_xor(c4, m); c5 += __shfl_xor(c5, m); c6 += __shfl_xor(c6, m); c7 += __shfl_xor(c7, m);
  }
  if (l == 0) {
    wc[w][0] = c0; wc[w][1] = c1; wc[w][2] = c2; wc[w][3] = c3;
    wc[w][4] = c4; wc[w][5] = c5; wc[w][6] = c6; wc[w][7] = c7;
  }
  __syncthreads();
  if (tid == 0) {
    int o = 0, t2 = 0;
    for (int e = 0; e < 8; e++) {
      cursor[e] = o;
      int cc = wc[0][e] + wc[1][e] + wc[2][e] + wc[3][e];
      for (int i = 0; i < cc; i += 128) {
        tile_e[t2] = e; tile_b[t2] = o + i; tile_c[t2] = (cc - i < 128) ? (cc - i) : 128; t2++;
      }
      o += cc;
    }
    for (; t2 < MAXT; t2++) tile_e[t2] = -1;
  }
}

__global__ __launch_bounds__(256) void scatter_kernel(const int* __restrict__ tok_e, const float* __restrict__ tok_w,
                                                      int* __restrict__ cursor, int* __restrict__ lists,
                                                      float* __restrict__ slotw) {
  int t = blockIdx.x * 256 + threadIdx.x;
#pragma unroll
  for (int s = 0; s < 2; s++) {
    int e = tok_e[t * 2 + s];
    int pos = atomicAdd(&cursor[e], 1);
    lists[pos] = t * 2 + s;
    slotw[pos] = tok_w[t * 2 + s];
  }
}

__global__ __launch_bounds__(256) void combine_kernel(float* __restrict__ out, const float* __restrict__ yp) {
  long i = (long)blockIdx.x * 256 + threadIdx.x;  // float4 index over 4M floats
  long n = i >> 8;
  long d = i & 255;
  float4 o = *(float4*)(out + (i << 2));
  const float4 a = *(const float4*)(yp + ((n * 2) << 10) + (d << 2));
  const float4 b = *(const float4*)(yp + ((n * 2 + 1) << 10) + (d << 2));
  o.x += a.x + b.x; o.y += a.y + b.y; o.z += a.z + b.z; o.w += a.w + b.w;
  *(float4*)(out + (i << 2)) = o;
}

extern "C" void kernel_launch(void* const* d_in, const int* in_sizes, int n_in,
                              void* d_out, int out_size, void* d_ws, size_t ws_size,
                              hipStream_t stream) {
  const float* x    = (const float*)d_in[0];
  const float* ln1g = (const float*)d_in[1];
  const float* ln1b = (const float*)d_in[2];
  const float* Wqkv = (const float*)d_in[3];
  const float* Wo   = (const float*)d_in[4];
  const float* ln2g = (const float*)d_in[5];
  const float* ln2b = (const float*)d_in[6];
  const float* Wg   = (const float*)d_in[7];
  const float* W1   = (const float*)d_in[8];
  const float* W2   = (const float*)d_in[9];
  float* out = (float*)d_out;
  char* ws = (char*)d_ws;

  size_t off = 0;
  auto alloc = [&](size_t b) { size_t o = off; off += (b + 255) & ~size_t(255); return o; };
  u16* WqkvTh = (u16*)(ws + alloc(3072ull * 1024 * 2));
  u16* WqkvTl = (u16*)(ws + alloc(3072ull * 1024 * 2));
  u16* WoTh   = (u16*)(ws + alloc(1024ull * 1024 * 2));
  u16* WoTl   = (u16*)(ws + alloc(1024ull * 1024 * 2));
  u16* W1T    = (u16*)(ws + alloc(8ull * 4096 * 1024 * 2));
  u16* W2T    = (u16*)(ws + alloc(8ull * 1024 * 4096 * 2));
  u16* hh     = (u16*)(ws + alloc(4096ull * 1024 * 2));
  u16* hl     = (u16*)(ws + alloc(4096ull * 1024 * 2));
  float* qkv  = (float*)(ws + alloc(4096ull * 3072 * 4));
  u16* atth   = (u16*)(ws + alloc(4096ull * 1024 * 2));
  u16* attl   = (u16*)(ws + alloc(4096ull * 1024 * 2));
  u16* moein  = (u16*)(ws + alloc(4096ull * 1024 * 2));
  u16* act    = (u16*)(ws + alloc(8192ull * 4096 * 2));
  float* WgT  = (float*)(ws + alloc(8ull * 1024 * 4));
  float* ypart = qkv;  // alias: qkv (50.3MB) dead after attention; ypart needs 33.6MB
  // K/V f16 planes alias into act (dead until FFN1): 4 planes x 8MB = 32MB < 67MB
  u16* Kh  = act;
  u16* Kl  = act + 4194304;
  u16* Vth = act + 2 * 4194304;
  u16* Vtl = act + 3 * 4194304;
  int* tok_e  = (int*)(ws + alloc(8192 * 4));
  float* tok_w = (float*)(ws + alloc(8192 * 4));
  int* cursor = (int*)(ws + alloc(64));
  int* lists  = (int*)(ws + alloc(8192 * 4));
  float* slotw = (float*)(ws + alloc(8192 * 4));
  int* tile_e = (int*)(ws + alloc(MAXT * 4));
  int* tile_b = (int*)(ws + alloc(MAXT * 4));
  int* tile_c = (int*)(ws + alloc(MAXT * 4));
  (void)in_sizes; (void)n_in; (void)out_size; (void)ws_size;

  dim3 blk(256), blk512(512);
  // weight transpose+convert (B^T layout for all GEMMs) + WgT for gate
  transpose_kernel<0><<<dim3(96, 32, 1), blk, 0, stream>>>(Wqkv, WqkvTh, WqkvTl, 1024, 3072);
  transpose_kernel<0><<<dim3(32, 32, 1), blk, 0, stream>>>(Wo, WoTh, WoTl, 1024, 1024);
  transpose_kernel<1><<<dim3(128, 32, 8), blk, 0, stream>>>(W1, W1T, nullptr, 1024, 4096);
  transpose_kernel<1><<<dim3(32, 128, 8), blk, 0, stream>>>(W2, W2T, nullptr, 4096, 1024);
  wg_transpose<<<dim3(32), blk, 0, stream>>>(Wg, WgT);
  // LN1 -> h (f16 hi/lo)
  ln_kernel<<<dim3(4096), blk, 0, stream>>>(x, ln1g, ln1b, hh, hl);
  // QKV = h @ Wqkv (split-f16 x3, 512 thr) -> f32
  gemm_kernel<0><<<dim3(24, 32), blk512, 0, stream>>>(hh, hl, WqkvTh, WqkvTl, 1024, 3072, 0,
                                                      nullptr, nullptr, nullptr, nullptr,
                                                      qkv, nullptr, nullptr, nullptr);
  // K/V pre-convert to split-f16 planes
  kv_prep<<<dim3(16, 16, 4), blk, 0, stream>>>(qkv, Kh, Kl, Vth, Vtl);
  // flash attention (balanced causal pairing: each block does 17 tile-steps)
  attn_kernel<<<dim3(8, 16, 4), blk, 0, stream>>>(qkv, Kh, Kl, Vth, Vtl, atth, attl);
  // x_resid = x + attn @ Wo (split-f16 x3, TN=64, 512 thr) -> d_out
  gemm_kernel<1><<<dim3(16, 32), blk512, 0, stream>>>(atth, attl, WoTh, WoTl, 1024, 1024, 0,
                                                      nullptr, nullptr, nullptr, nullptr,
                                                      out, nullptr, x, nullptr);
  // routing (f32, WgT coalesced, no atomics) + fused LN2 -> moein
  gate_kernel<<<dim3(1024), blk, 0, stream>>>(out, ln2g, ln2b, WgT, tok_e, tok_w, moein);
  // plan: histogram tok_e + tile table + cursor init (single block)
  plan_kernel<<<dim3(1), blk, 0, stream>>>(tok_e, cursor, tile_e, tile_b, tile_c);
  scatter_kernel<<<dim3(16), blk, 0, stream>>>(tok_e, tok_w, cursor, lists, slotw);
  // FFN1: gather tokens, gelu(h @ W1[e]) -> act bf16 (TN=128, XCD-chunked, 512 thr)
  gemm_kernel<2><<<dim3(8 * 9 * 32), blk512, 0, stream>>>(moein, nullptr, W1T, nullptr, 1024, 4096, 4096,
                                                          lists, tile_e, tile_b, tile_c,
                                                          nullptr, act, nullptr, nullptr);
  // FFN2: act @ W2[e] * gate -> ypart scatter (TN=128, XCD-chunked, counted-vmcnt pipeline)
  gemm_kernel<3><<<dim3(8 * 9 * 8), blk512, 0, stream>>>(act, nullptr, W2T, nullptr, 4096, 1024, 1024,
                                                         lists, tile_e, tile_b, tile_c,
                                                         ypart, nullptr, nullptr, slotw);
  // out = x_resid + y0 + y1
  combine_kernel<<<dim3(4096), blk, 0, stream>>>(out, ypart);
}

// Round 14
// 530.657 us; speedup vs baseline: 1.0931x; 1.0316x over previous
//
#include <hip/hip_runtime.h>

// B=4 S=1024 D=1024 H=16 HD=64 E=8 TOPK=2 F=4096 ; tokens N=4096
typedef unsigned short u16;
typedef _Float16 f16x8 __attribute__((ext_vector_type(8)));
typedef __bf16   bf16x8 __attribute__((ext_vector_type(8)));
typedef float    f32x4 __attribute__((ext_vector_type(4)));

struct __align__(8) U16x4 { u16 v[4]; };

#define MAXT 72

__device__ __forceinline__ u16 f2b(float f) {            // f32 -> bf16 RNE bits
  unsigned u = __builtin_bit_cast(unsigned, f);
  return (u16)((u + 0x7FFFu + ((u >> 16) & 1u)) >> 16);
}
__device__ __forceinline__ u16 f2h(float f) { return __builtin_bit_cast(u16, (_Float16)f); }
__device__ __forceinline__ u16 f2h_lo(float f) {
  _Float16 h = (_Float16)f;
  return __builtin_bit_cast(u16, (_Float16)(f - (float)h));
}
__device__ __forceinline__ void llds16(const void* g, void* l) {
  __builtin_amdgcn_global_load_lds((const __attribute__((address_space(1))) unsigned int*)g,
                                   (__attribute__((address_space(3))) unsigned int*)l, 16, 0, 0);
}
__device__ __forceinline__ f32x4 mmf(f16x8 a, f16x8 b, f32x4 c) {
  return __builtin_amdgcn_mfma_f32_16x16x32_f16(a, b, c, 0, 0, 0);
}
__device__ __forceinline__ f32x4 mmb(bf16x8 a, bf16x8 b, f32x4 c) {
  return __builtin_amdgcn_mfma_f32_16x16x32_bf16(a, b, c, 0, 0, 0);
}

// ---------------- transpose + convert: src [R,C] f32 -> dst [C,R] f16(hi/lo) or bf16 ----
template<int OUT> // 0: f16 split pair, 1: bf16 single
__global__ __launch_bounds__(256) void transpose_kernel(const float* __restrict__ src,
                                                        u16* __restrict__ d0, u16* __restrict__ d1,
                                                        int R, int C) {
  __shared__ float t[32][33];
  long zo = (long)blockIdx.z * R * C;
  int r0 = blockIdx.y << 5, c0 = blockIdx.x << 5;
  int tid = threadIdx.x;
  {
    int r = tid >> 3, c = (tid & 7) << 2;
    float4 v = *(const float4*)(src + zo + (long)(r0 + r) * C + c0 + c);
    t[r][c] = v.x; t[r][c + 1] = v.y; t[r][c + 2] = v.z; t[r][c + 3] = v.w;
  }
  __syncthreads();
  int c = tid >> 3, rg = (tid & 7) << 2;
  long o = zo + (long)(c0 + c) * R + r0 + rg;
  U16x4 a, b2;
#pragma unroll
  for (int i = 0; i < 4; i++) {
    float f = t[rg + i][c];
    if (OUT == 0) { a.v[i] = f2h(f); b2.v[i] = f2h_lo(f); }
    else a.v[i] = f2b(f);
  }
  *(U16x4*)(d0 + o) = a;
  if (OUT == 0) *(U16x4*)(d1 + o) = b2;
}

// ---------------- Wg [1024,8] -> WgT [8,1024] (tiny, for coalesced gate loads) ---------
__global__ __launch_bounds__(256) void wg_transpose(const float* __restrict__ Wg,
                                                    float* __restrict__ WgT) {
  int idx = blockIdx.x * 256 + threadIdx.x;   // 8192 elements
  int d = idx >> 3, e = idx & 7;
  WgT[e * 1024 + d] = Wg[idx];
}

// ---------------- LayerNorm row kernel (LN1 only; LN2 fused into gate) ----------------
__global__ __launch_bounds__(256) void ln_kernel(const float* __restrict__ x, const float* __restrict__ g,
                                                 const float* __restrict__ bt,
                                                 u16* __restrict__ d0, u16* __restrict__ d1) {
  long row = blockIdx.x;
  int tid = threadIdx.x;
  const float4 v = *(const float4*)(x + (row << 10) + (tid << 2));
  float s = v.x + v.y + v.z + v.w;
  float q = v.x * v.x + v.y * v.y + v.z * v.z + v.w * v.w;
#pragma unroll
  for (int m = 1; m < 64; m <<= 1) { s += __shfl_xor(s, m); q += __shfl_xor(q, m); }
  __shared__ float rs[4], rq[4];
  if ((tid & 63) == 0) { rs[tid >> 6] = s; rq[tid >> 6] = q; }
  __syncthreads();
  s = rs[0] + rs[1] + rs[2] + rs[3];
  q = rq[0] + rq[1] + rq[2] + rq[3];
  float mu = s * (1.f / 1024.f);
  float inv = 1.f / sqrtf(q * (1.f / 1024.f) - mu * mu + 1e-5f);
  float4 gg = *(const float4*)(g + (tid << 2));
  float4 bb = *(const float4*)(bt + (tid << 2));
  float o0 = (v.x - mu) * inv * gg.x + bb.x;
  float o1 = (v.y - mu) * inv * gg.y + bb.y;
  float o2 = (v.z - mu) * inv * gg.z + bb.z;
  float o3 = (v.w - mu) * inv * gg.w + bb.w;
  long o = (row << 10) + (tid << 2);
  U16x4 a, b2;
  a.v[0] = f2h(o0); a.v[1] = f2h(o1); a.v[2] = f2h(o2); a.v[3] = f2h(o3);
  b2.v[0] = f2h_lo(o0); b2.v[1] = f2h_lo(o1); b2.v[2] = f2h_lo(o2); b2.v[3] = f2h_lo(o3);
  *(U16x4*)(d0 + o) = a; *(U16x4*)(d1 + o) = b2;
}

// ------- unified tiled GEMM, 128xTN xK BK=64, A[M,K] x Bt[N,K], 512 thr / 8 waves -------
// Wave grid 2x4: wave covers 64 x (TN/4) of the tile (acc[4][NF], NF = TN/64).
// MODE 0: split f16 x3 -> f32 out (QKV), TN=128, single-buffered (64KB).
// MODE 1: split f16 x3 -> f32 + resid (Wo), TN=64, single-buffered.
// MODE 2: bf16, A gathered via lists -> gelu -> bf16 (FFN1), TN=128, XCD-chunked, 32KB.
// MODE 3: bf16, A direct grouped -> scatter f32 w*acc (FFN2), TN=128, XCD-chunked, 32KB.
template<int MODE>
__global__ __launch_bounds__(512, 1) void gemm_kernel(
    const u16* __restrict__ Ah, const u16* __restrict__ Al,
    const u16* __restrict__ Bh, const u16* __restrict__ Bl,
    int K, int ldc, int Nexp,
    const int* __restrict__ lists, const int* __restrict__ tile_e,
    const int* __restrict__ tile_b, const int* __restrict__ tile_c,
    float* __restrict__ outf, u16* __restrict__ outb,
    const float* __restrict__ resid, const float* __restrict__ slotw) {
  constexpr bool SPLIT = (MODE < 2);
  constexpr int TN = (MODE == 1) ? 64 : 128;   // tile N
  constexpr int NF = TN >> 6;                  // n-frags per wave (2 or 1)
  constexpr int NB = TN >> 6;                  // B staging chunks per thread (2 or 1)
  constexpr int SMEM = SPLIT ? 65536 : 32768;
  __shared__ __align__(16) char smem[SMEM];
  char* pAh = smem;
  char* pBh = smem + 16384;
  char* pAl = smem + 32768;   // SPLIT only
  char* pBl = smem + 49152;   // SPLIT only
  const int tid = threadIdx.x, w = tid >> 6, l = tid & 63;
  int n0;
  int grbase = 0, rowsv = 128;
  long m0 = 0;
  if (MODE >= 2) {
    // Chunked XCD swizzle: XCD c owns 9 consecutive y-tiles (A-panel sharers colocate
    // on one L2; an expert's tiles stay mostly within one XCD for W reuse).
    int lin = blockIdx.x;
    int c = lin & 7, k = lin >> 3;
    int ty = c * 9 + (k % 9);      // tile index [0,72)
    int tx = k / 9;                // n-tile
    n0 = tx * TN;
    int e = tile_e[ty];
    if (e < 0) return;
    grbase = tile_b[ty];
    rowsv = tile_c[ty];
    Bh += (long)e * Nexp * K;
  } else {
    n0 = blockIdx.x * TN;
    m0 = (long)blockIdx.y << 7;
  }

  const u16 *as0[2], *as1[2], *bs0[2], *bs1[2];
  int dstA[2], dstB[2];
#pragma unroll
  for (int i = 0; i < 2; i++) {        // A: 1024 chunks of 16B over 512 threads
    int chunk = i * 512 + tid;
    int row = chunk >> 3, c16 = chunk & 7;
    int scol = (c16 << 4) ^ ((row & 7) << 4);   // pre-swizzled source byte col
    dstA[i] = chunk << 4;
    long ar;
    if (MODE == 2) {
      int vlu = lists[(row < rowsv) ? (grbase + row) : grbase];
      ar = (long)(vlu >> 1);
    } else if (MODE == 3) {
      ar = grbase + ((row < rowsv) ? row : 0);
    } else {
      ar = m0 + row;
    }
    long ao = ar * (long)K + (scol >> 1);
    as0[i] = Ah + ao;
    if (SPLIT) as1[i] = Al + ao;
  }
#pragma unroll
  for (int i = 0; i < NB; i++) {       // B: TN*8 chunks of 16B over 512 threads
    int chunk = i * 512 + tid;
    int row = chunk >> 3, c16 = chunk & 7;
    int scol = (c16 << 4) ^ ((row & 7) << 4);
    dstB[i] = chunk << 4;
    long bo = (long)(n0 + row) * K + (scol >> 1);
    bs0[i] = Bh + bo;
    if (SPLIT) bs1[i] = Bl + bo;
  }

  f32x4 acc[4][NF];
#pragma unroll
  for (int i = 0; i < 4; i++)
#pragma unroll
    for (int j = 0; j < NF; j++) acc[i][j] = (f32x4){0.f, 0.f, 0.f, 0.f};

  const int wr = (w >> 2) << 6;            // wave-row: 2 rows of 64
  const int wc = (w & 3) * (TN / 4);       // wave-col: 4 cols of TN/4
  const int nkt = K >> 6;
  for (int kt = 0; kt < nkt; ++kt) {
    if (kt) __syncthreads();
#pragma unroll
    for (int i = 0; i < 2; i++) {
      llds16(as0[i] + (kt << 6), pAh + dstA[i]);
      if (SPLIT) llds16(as1[i] + (kt << 6), pAl + dstA[i]);
    }
#pragma unroll
    for (int i = 0; i < NB; i++) {
      llds16(bs0[i] + (kt << 6), pBh + dstB[i]);
      if (SPLIT) llds16(bs1[i] + (kt << 6), pBl + dstB[i]);
    }
    __syncthreads();
#pragma unroll
    for (int kc = 0; kc < 2; kc++) {
      const int kby = (kc << 6) + ((l >> 4) << 4);
      int aoff[4], boff[NF];
#pragma unroll
      for (int mf = 0; mf < 4; mf++) { int row = wr + (mf << 4) + (l & 15); aoff[mf] = (row << 7) + (kby ^ ((row & 7) << 4)); }
#pragma unroll
      for (int nf = 0; nf < NF; nf++) { int row = wc + (nf << 4) + (l & 15); boff[nf] = (row << 7) + (kby ^ ((row & 7) << 4)); }
      if (SPLIT) {
        f16x8 a0[4], a1[4], b0[NF], b1[NF];
#pragma unroll
        for (int mf = 0; mf < 4; mf++) {
          a0[mf] = *(const f16x8*)(pAh + aoff[mf]);
          a1[mf] = *(const f16x8*)(pAl + aoff[mf]);
        }
#pragma unroll
        for (int nf = 0; nf < NF; nf++) {
          b0[nf] = *(const f16x8*)(pBh + boff[nf]);
          b1[nf] = *(const f16x8*)(pBl + boff[nf]);
        }
#pragma unroll
        for (int mf = 0; mf < 4; mf++)
#pragma unroll
          for (int nf = 0; nf < NF; nf++) {
            acc[mf][nf] = mmf(a0[mf], b0[nf], acc[mf][nf]);
            acc[mf][nf] = mmf(a0[mf], b1[nf], acc[mf][nf]);
            acc[mf][nf] = mmf(a1[mf], b0[nf], acc[mf][nf]);
          }
      } else {
        bf16x8 a0[4], b0[NF];
#pragma unroll
        for (int mf = 0; mf < 4; mf++) a0[mf] = *(const bf16x8*)(pAh + aoff[mf]);
#pragma unroll
        for (int nf = 0; nf < NF; nf++) b0[nf] = *(const bf16x8*)(pBh + boff[nf]);
#pragma unroll
        for (int mf = 0; mf < 4; mf++)
#pragma unroll
          for (int nf = 0; nf < NF; nf++) acc[mf][nf] = mmb(a0[mf], b0[nf], acc[mf][nf]);
      }
    }
  }

  // epilogue: C/D layout col = lane&15, row = (lane>>4)*4 + reg
#pragma unroll
  for (int mf = 0; mf < 4; mf++) {
#pragma unroll
    for (int r = 0; r < 4; r++) {
      const int lrow = wr + (mf << 4) + ((l >> 4) << 2) + r;
      if (MODE >= 2 && lrow >= rowsv) continue;
      float gw = 0.f; long orow = 0;
      if (MODE == 3) { int gr = grbase + lrow; orow = (long)lists[gr] * ldc; gw = slotw[gr]; }
#pragma unroll
      for (int nf = 0; nf < NF; nf++) {
        const int col = n0 + wc + (nf << 4) + (l & 15);
        float v = acc[mf][nf][r];
        if (MODE == 0) {
          outf[(m0 + lrow) * (long)ldc + col] = v;
        } else if (MODE == 1) {
          long ix = (m0 + lrow) * (long)ldc + col;
          outf[ix] = v + resid[ix];
        } else if (MODE == 2) {
          // gelu(v) = v * sigmoid(1.5957691 v + 0.0713549 v^3)  (exact tanh-form identity)
          float t = v * (1.59576912f + 0.07135539f * v * v);
          float u = v * __builtin_amdgcn_rcpf(1.f + __expf(-t));
          outb[(long)(grbase + lrow) * ldc + col] = f2b(u);
        } else {
          outf[orow + col] = v * gw;
        }
      }
    }
  }
}

// ---------------- K/V pre-convert: per (b,h) planes Kh/Kl [1024][64], Vth/Vtl [64][1024] ----
__global__ __launch_bounds__(256) void kv_prep(const float* __restrict__ qkv,
                                               u16* __restrict__ Kh, u16* __restrict__ Kl,
                                               u16* __restrict__ Vth, u16* __restrict__ Vtl) {
  __shared__ float t[64][65];
  const int tid = threadIdx.x;
  const int kb = blockIdx.x, h = blockIdx.y, b = blockIdx.z;
  const long bb = ((long)b) << 10;
  const int hoff = h << 6;
  const long head = ((long)(b * 16 + h)) << 16;   // 65536 elems per head-plane
  {
    int rr = tid >> 4, c = (tid & 15) << 2;
#pragma unroll
    for (int p = 0; p < 4; p++) {
      int r = rr + p * 16;
      const float* base = qkv + (bb + kb * 64 + r) * 3072 + hoff + c;
      float4 u = *(const float4*)(base + 1024);
      U16x4 a, lo;
      a.v[0] = f2h(u.x); a.v[1] = f2h(u.y); a.v[2] = f2h(u.z); a.v[3] = f2h(u.w);
      lo.v[0] = f2h_lo(u.x); lo.v[1] = f2h_lo(u.y); lo.v[2] = f2h_lo(u.z); lo.v[3] = f2h_lo(u.w);
      long o = head + (long)(kb * 64 + r) * 64 + c;
      *(U16x4*)(Kh + o) = a; *(U16x4*)(Kl + o) = lo;
      float4 v = *(const float4*)(base + 2048);
      t[r][c] = v.x; t[r][c + 1] = v.y; t[r][c + 2] = v.z; t[r][c + 3] = v.w;
    }
  }
  __syncthreads();
  {
    int hd = tid >> 2, k4 = (tid & 3) << 4;
#pragma unroll
    for (int q = 0; q < 4; q++) {
      U16x4 a, lo;
#pragma unroll
      for (int j = 0; j < 4; j++) {
        float f = t[k4 + q * 4 + j][hd];
        a.v[j] = f2h(f); lo.v[j] = f2h_lo(f);
      }
      long o = head + (long)hd * 1024 + kb * 64 + k4 + q * 4;
      *(U16x4*)(Vth + o) = a; *(U16x4*)(Vtl + o) = lo;
    }
  }
}

// ---------------- flash attention v2: prepped K/V planes, llds staging, balanced pairing ----
__global__ __launch_bounds__(256, 1) void attn_kernel(const float* __restrict__ qkv,
                                                      const u16* __restrict__ Kh, const u16* __restrict__ Kl,
                                                      const u16* __restrict__ Vth, const u16* __restrict__ Vtl,
                                                      u16* __restrict__ oh, u16* __restrict__ ol) {
  __shared__ u16 kh[4096], kl[4096];       // K tile [64 key][64 hd], swizzled
  __shared__ u16 vh[4096], vl[4096];       // V^T tile [64 hd][64 key], swizzled
  __shared__ u16 ph[4][1024], pl[4][1024]; // per-wave P [16 m][64 k]
  const int tid = threadIdx.x, w = tid >> 6, l = tid & 63;
  const int qbi = blockIdx.x, hh_ = blockIdx.y, b = blockIdx.z;
  const long bb = ((long)b) << 10;
  const int hoff = hh_ << 6;
  const long head = ((long)(b * 16 + hh_)) << 16;

  // staging descriptors (2 chunks of 16B per thread per plane)
  const u16 *ks0[2], *ks1[2], *vs0[2], *vs1[2];
  int db[2];
#pragma unroll
  for (int i = 0; i < 2; i++) {
    int chunk = i * 256 + tid;
    int row = chunk >> 3, c16 = chunk & 7;
    int sc = ((c16 << 4) ^ ((row & 7) << 4)) >> 1;
    db[i] = chunk << 4;
    ks0[i] = Kh + head + row * 64 + sc;
    ks1[i] = Kl + head + row * 64 + sc;
    vs0[i] = Vth + head + (long)row * 1024 + sc;
    vs1[i] = Vtl + head + (long)row * 1024 + sc;
  }

  for (int pass = 0; pass < 2; ++pass) {
    const int qb = (pass ? qbi : (15 - qbi)) << 6;   // long pass first; total 17 tiles/block
    // load Q fragments (split f16)
    f16x8 q0[2], q1[2];
    {
      const long qrow = bb + qb + (w << 4) + (l & 15);
      const float* qp = qkv + qrow * 3072 + hoff + ((l >> 4) << 3);
#pragma unroll
      for (int kc = 0; kc < 2; kc++) {
        float4 u0 = *(const float4*)(qp + (kc << 5));
        float4 u1 = *(const float4*)(qp + (kc << 5) + 4);
        float vv[8] = {u0.x, u0.y, u0.z, u0.w, u1.x, u1.y, u1.z, u1.w};
#pragma unroll
        for (int j = 0; j < 8; j++) {
          _Float16 hi = (_Float16)vv[j];
          q0[kc][j] = hi;
          q1[kc][j] = (_Float16)(vv[j] - (float)hi);
        }
      }
    }

    f32x4 o[4];
#pragma unroll
    for (int nf = 0; nf < 4; nf++) o[nf] = (f32x4){0.f, 0.f, 0.f, 0.f};
    float mr[4] = {-1e30f, -1e30f, -1e30f, -1e30f};
    float lr[4] = {0.f, 0.f, 0.f, 0.f};
    const int ktm = qb >> 6;

    for (int kt = 0; kt <= ktm; ++kt) {
      __syncthreads();
#pragma unroll
      for (int i = 0; i < 2; i++) {
        llds16(ks0[i] + (kt << 12), (char*)kh + db[i]);
        llds16(ks1[i] + (kt << 12), (char*)kl + db[i]);
        llds16(vs0[i] + (kt << 6), (char*)vh + db[i]);
        llds16(vs1[i] + (kt << 6), (char*)vl + db[i]);
      }
      __syncthreads();

      // QK^T (split x3)
      f32x4 s[4];
#pragma unroll
      for (int nf = 0; nf < 4; nf++) s[nf] = (f32x4){0.f, 0.f, 0.f, 0.f};
#pragma unroll
      for (int kc = 0; kc < 2; kc++) {
        const int kby = (kc << 6) + ((l >> 4) << 4);
#pragma unroll
        for (int nf = 0; nf < 4; nf++) {
          int row = (nf << 4) + (l & 15);
          int off = (row << 7) + (kby ^ ((row & 7) << 4));
          f16x8 k0 = *(const f16x8*)((const char*)kh + off);
          f16x8 k1 = *(const f16x8*)((const char*)kl + off);
          s[nf] = mmf(q0[kc], k0, s[nf]);
          s[nf] = mmf(q0[kc], k1, s[nf]);
          s[nf] = mmf(q1[kc], k0, s[nf]);
        }
      }
      const bool lastt = (kt == ktm);
#pragma unroll
      for (int nf = 0; nf < 4; nf++)
#pragma unroll
        for (int r = 0; r < 4; r++) {
          float sc = s[nf][r] * 0.125f;
          if (lastt) {
            int keyg = (kt << 6) + (nf << 4) + (l & 15);
            int qg = qb + (w << 4) + ((l >> 4) << 2) + r;
            if (keyg > qg) sc = -1e30f;
          }
          s[nf][r] = sc;
        }
      float alpha[4];
#pragma unroll
      for (int r = 0; r < 4; r++) {
        float mx = fmaxf(fmaxf(s[0][r], s[1][r]), fmaxf(s[2][r], s[3][r]));
        mx = fmaxf(mx, __shfl_xor(mx, 1));
        mx = fmaxf(mx, __shfl_xor(mx, 2));
        mx = fmaxf(mx, __shfl_xor(mx, 4));
        mx = fmaxf(mx, __shfl_xor(mx, 8));
        float mn = fmaxf(mr[r], mx);
        float su = 0.f;
#pragma unroll
        for (int nf = 0; nf < 4; nf++) { float pv = __expf(s[nf][r] - mn); s[nf][r] = pv; su += pv; }
        su += __shfl_xor(su, 1); su += __shfl_xor(su, 2);
        su += __shfl_xor(su, 4); su += __shfl_xor(su, 8);
        alpha[r] = __expf(mr[r] - mn);
        lr[r] = lr[r] * alpha[r] + su;
        mr[r] = mn;
      }
#pragma unroll
      for (int nf = 0; nf < 4; nf++)
#pragma unroll
        for (int r = 0; r < 4; r++) o[nf][r] *= alpha[r];
      // write P (hi/lo) to per-wave LDS
#pragma unroll
      for (int nf = 0; nf < 4; nf++)
#pragma unroll
        for (int r = 0; r < 4; r++) {
          int m = ((l >> 4) << 2) + r, k = (nf << 4) + (l & 15);
          int off = (m << 7) + ((k << 1) ^ ((m & 7) << 4));
          float pv = s[nf][r];
          _Float16 hi = (_Float16)pv;
          *(u16*)((char*)&ph[w][0] + off) = __builtin_bit_cast(u16, hi);
          *(u16*)((char*)&pl[w][0] + off) = __builtin_bit_cast(u16, (_Float16)(pv - (float)hi));
        }
      // PV (split x3)
#pragma unroll
      for (int kc = 0; kc < 2; kc++) {
        const int kby = (kc << 6) + ((l >> 4) << 4);
        const int mm = l & 15;
        int poff = (mm << 7) + (kby ^ ((mm & 7) << 4));
        f16x8 p0 = *(const f16x8*)((const char*)&ph[w][0] + poff);
        f16x8 p1 = *(const f16x8*)((const char*)&pl[w][0] + poff);
#pragma unroll
        for (int nf = 0; nf < 4; nf++) {
          int row = (nf << 4) + (l & 15);
          int off = (row << 7) + (kby ^ ((row & 7) << 4));
          f16x8 v0 = *(const f16x8*)((const char*)vh + off);
          f16x8 v1 = *(const f16x8*)((const char*)vl + off);
          o[nf] = mmf(p0, v0, o[nf]);
          o[nf] = mmf(p0, v1, o[nf]);
          o[nf] = mmf(p1, v0, o[nf]);
        }
      }
    }
    // store O split to f16 planes
#pragma unroll
    for (int nf = 0; nf < 4; nf++)
#pragma unroll
      for (int r = 0; r < 4; r++) {
        int lrow = (w << 4) + ((l >> 4) << 2) + r;
        float v = o[nf][r] / lr[r];
        long ix = (bb + qb + lrow) * 1024 + hoff + (nf << 4) + (l & 15);
        _Float16 hi = (_Float16)v;
        oh[ix] = __builtin_bit_cast(u16, hi);
        ol[ix] = __builtin_bit_cast(u16, (_Float16)(v - (float)hi));
      }
  }
}

// ------- gating v2: f32 LN + logits (WgT coalesced) + top2, fused LN2 out, NO atomics ----
__global__ __launch_bounds__(256) void gate_kernel(const float* __restrict__ xr, const float* __restrict__ g,
                                                   const float* __restrict__ b, const float* __restrict__ WgT,
                                                   int* __restrict__ tok_e, float* __restrict__ tok_w,
                                                   u16* __restrict__ moe) {
  int w = threadIdx.x >> 6, l = threadIdx.x & 63;
  long t = (long)blockIdx.x * 4 + w;
  const float* row = xr + (t << 10);
  float4 xv[4]; float s = 0.f, q = 0.f;
#pragma unroll
  for (int i = 0; i < 4; i++) {
    float4 v = *(const float4*)(row + (i << 8) + (l << 2));
    xv[i] = v;
    s += v.x + v.y + v.z + v.w;
    q += v.x * v.x + v.y * v.y + v.z * v.z + v.w * v.w;
  }
#pragma unroll
  for (int m = 1; m < 64; m <<= 1) { s += __shfl_xor(s, m); q += __shfl_xor(q, m); }
  float mu = s * (1.f / 1024.f);
  float inv = 1.f / sqrtf(q * (1.f / 1024.f) - mu * mu + 1e-5f);
  float acc[8] = {0.f, 0.f, 0.f, 0.f, 0.f, 0.f, 0.f, 0.f};
#pragma unroll
  for (int i = 0; i < 4; i++) {
    int d0 = (i << 8) + (l << 2);
    float4 gg = *(const float4*)(g + d0);
    float4 bb = *(const float4*)(b + d0);
    float x0 = (xv[i].x - mu) * inv * gg.x + bb.x;
    float x1 = (xv[i].y - mu) * inv * gg.y + bb.y;
    float x2 = (xv[i].z - mu) * inv * gg.z + bb.z;
    float x3 = (xv[i].w - mu) * inv * gg.w + bb.w;
    U16x4 st;
    st.v[0] = f2b(x0); st.v[1] = f2b(x1); st.v[2] = f2b(x2); st.v[3] = f2b(x3);
    *(U16x4*)(moe + (t << 10) + d0) = st;
#pragma unroll
    for (int e = 0; e < 8; e++) {
      float4 wq = *(const float4*)(WgT + (e << 10) + d0);
      acc[e] += x0 * wq.x + x1 * wq.y + x2 * wq.z + x3 * wq.w;
    }
  }
#pragma unroll
  for (int e = 0; e < 8; e++)
#pragma unroll
    for (int m = 1; m < 64; m <<= 1) acc[e] += __shfl_xor(acc[e], m);
  if (l == 0) {
    int e0 = 0; float v0 = acc[0];
#pragma unroll
    for (int e = 1; e < 8; e++) if (acc[e] > v0) { v0 = acc[e]; e0 = e; }
    int e1 = (e0 == 0) ? 1 : 0; float v1 = acc[e1];
#pragma unroll
    for (int e = 0; e < 8; e++) if (e != e0 && acc[e] > v1) { v1 = acc[e]; e1 = e; }
    float w0 = 1.f / (1.f + __expf(v1 - v0));
    tok_e[t * 2] = e0; tok_e[t * 2 + 1] = e1;
    tok_w[t * 2] = w0; tok_w[t * 2 + 1] = 1.f - w0;
  }
}

// ------- plan v2: 256-thread histogram of tok_e (named counters + shuffle reduce) -------
__global__ __launch_bounds__(256) void plan_kernel(const int* __restrict__ tok_e, int* __restrict__ cursor,
                                                   int* __restrict__ tile_e, int* __restrict__ tile_b,
                                                   int* __restrict__ tile_c) {
  __shared__ int wc[4][8];
  int tid = threadIdx.x, w = tid >> 6, l = tid & 63;
  int c0 = 0, c1 = 0, c2 = 0, c3 = 0, c4 = 0, c5 = 0, c6 = 0, c7 = 0;
  for (int k = 0; k < 32; k++) {
    int v = tok_e[(w << 11) + (k << 6) + l];
    c0 += (v == 0); c1 += (v == 1); c2 += (v == 2); c3 += (v == 3);
    c4 += (v == 4); c5 += (v == 5); c6 += (v == 6); c7 += (v == 7);
  }
#pragma unroll
  for (int m = 1; m < 64; m <<= 1) {
    c0 += __shfl_xor(c0, m); c1 += __shfl_xor(c1, m); c2 += __shfl_xor(c2, m); c3 += __shfl_xor(c3, m);
    c4 += __shfl_xor(c4, m); c5 += __shfl_xor(c5, m); c6 += __shfl_xor(c6, m); c7 += __shfl_xor(c7, m);
  }
  if (l == 0) {
    wc[w][0] = c0; wc[w][1] = c1; wc[w][2] = c2; wc[w][3] = c3;
    wc[w][4] = c4; wc[w][5] = c5; wc[w][6] = c6; wc[w][7] = c7;
  }
  __syncthreads();
  if (tid == 0) {
    int o = 0, t2 = 0;
    for (int e = 0; e < 8; e++) {
      cursor[e] = o;
      int cc = wc[0][e] + wc[1][e] + wc[2][e] + wc[3][e];
      for (int i = 0; i < cc; i += 128) {
        tile_e[t2] = e; tile_b[t2] = o + i; tile_c[t2] = (cc - i < 128) ? (cc - i) : 128; t2++;
      }
      o += cc;
    }
    for (; t2 < MAXT; t2++) tile_e[t2] = -1;
  }
}

// ------- scatter v2: deterministic ballot-scan compaction, NO atomics ---------------------
// Block e compacts all slots with tok_e[slot]==e in ascending slot order.
__global__ __launch_bounds__(256) void scatter_kernel(const int* __restrict__ tok_e,
                                                      const float* __restrict__ tok_w,
                                                      const int* __restrict__ cursor,
                                                      int* __restrict__ lists,
                                                      float* __restrict__ slotw) {
  const int e = blockIdx.x;
  const int tid = threadIdx.x, w = tid >> 6, l = tid & 63;
  __shared__ int wbase[4];
  __shared__ int running;
  if (tid == 0) running = cursor[e];
  __syncthreads();
  for (int base = 0; base < 8192; base += 256) {
    int slot = base + tid;
    bool m = (tok_e[slot] == e);
    unsigned long long mask = __ballot(m);
    int prefix = __popcll(mask & ((1ull << l) - 1ull));
    if (l == 0) wbase[w] = __popcll(mask);
    __syncthreads();
    int off = running + prefix;
#pragma unroll
    for (int i = 0; i < 3; i++) if (w > i) off += wbase[i];
    if (m) { lists[off] = slot; slotw[off] = tok_w[slot]; }
    int total = wbase[0] + wbase[1] + wbase[2] + wbase[3];
    __syncthreads();
    if (tid == 0) running += total;
    __syncthreads();
  }
}

__global__ __launch_bounds__(256) void combine_kernel(float* __restrict__ out, const float* __restrict__ yp) {
  long i = (long)blockIdx.x * 256 + threadIdx.x;  // float4 index over 4M floats
  long n = i >> 8;
  long d = i & 255;
  float4 o = *(float4*)(out + (i << 2));
  const float4 a = *(const float4*)(yp + ((n * 2) << 10) + (d << 2));
  const float4 b = *(const float4*)(yp + ((n * 2 + 1) << 10) + (d << 2));
  o.x += a.x + b.x; o.y += a.y + b.y; o.z += a.z + b.z; o.w += a.w + b.w;
  *(float4*)(out + (i << 2)) = o;
}

extern "C" void kernel_launch(void* const* d_in, const int* in_sizes, int n_in,
                              void* d_out, int out_size, void* d_ws, size_t ws_size,
                              hipStream_t stream) {
  const float* x    = (const float*)d_in[0];
  const float* ln1g = (const float*)d_in[1];
  const float* ln1b = (const float*)d_in[2];
  const float* Wqkv = (const float*)d_in[3];
  const float* Wo   = (const float*)d_in[4];
  const float* ln2g = (const float*)d_in[5];
  const float* ln2b = (const float*)d_in[6];
  const float* Wg   = (const float*)d_in[7];
  const float* W1   = (const float*)d_in[8];
  const float* W2   = (const float*)d_in[9];
  float* out = (float*)d_out;
  char* ws = (char*)d_ws;

  size_t off = 0;
  auto alloc = [&](size_t b) { size_t o = off; off += (b + 255) & ~size_t(255); return o; };
  u16* WqkvTh = (u16*)(ws + alloc(3072ull * 1024 * 2));
  u16* WqkvTl = (u16*)(ws + alloc(3072ull * 1024 * 2));
  u16* WoTh   = (u16*)(ws + alloc(1024ull * 1024 * 2));
  u16* WoTl   = (u16*)(ws + alloc(1024ull * 1024 * 2));
  u16* W1T    = (u16*)(ws + alloc(8ull * 4096 * 1024 * 2));
  u16* W2T    = (u16*)(ws + alloc(8ull * 1024 * 4096 * 2));
  u16* hh     = (u16*)(ws + alloc(4096ull * 1024 * 2));
  u16* hl     = (u16*)(ws + alloc(4096ull * 1024 * 2));
  float* qkv  = (float*)(ws + alloc(4096ull * 3072 * 4));
  u16* atth   = (u16*)(ws + alloc(4096ull * 1024 * 2));
  u16* attl   = (u16*)(ws + alloc(4096ull * 1024 * 2));
  u16* moein  = (u16*)(ws + alloc(4096ull * 1024 * 2));
  u16* act    = (u16*)(ws + alloc(8192ull * 4096 * 2));
  float* WgT  = (float*)(ws + alloc(8ull * 1024 * 4));
  float* ypart = qkv;  // alias: qkv (50.3MB) dead after attention; ypart needs 33.6MB
  // K/V f16 planes alias into act (dead until FFN1): 4 planes x 8MB = 32MB < 67MB
  u16* Kh  = act;
  u16* Kl  = act + 4194304;
  u16* Vth = act + 2 * 4194304;
  u16* Vtl = act + 3 * 4194304;
  int* tok_e  = (int*)(ws + alloc(8192 * 4));
  float* tok_w = (float*)(ws + alloc(8192 * 4));
  int* cursor = (int*)(ws + alloc(64));
  int* lists  = (int*)(ws + alloc(8192 * 4));
  float* slotw = (float*)(ws + alloc(8192 * 4));
  int* tile_e = (int*)(ws + alloc(MAXT * 4));
  int* tile_b = (int*)(ws + alloc(MAXT * 4));
  int* tile_c = (int*)(ws + alloc(MAXT * 4));
  (void)in_sizes; (void)n_in; (void)out_size; (void)ws_size;

  dim3 blk(256), blk512(512);
  // weight transpose+convert (B^T layout for all GEMMs) + WgT for gate
  transpose_kernel<0><<<dim3(96, 32, 1), blk, 0, stream>>>(Wqkv, WqkvTh, WqkvTl, 1024, 3072);
  transpose_kernel<0><<<dim3(32, 32, 1), blk, 0, stream>>>(Wo, WoTh, WoTl, 1024, 1024);
  transpose_kernel<1><<<dim3(128, 32, 8), blk, 0, stream>>>(W1, W1T, nullptr, 1024, 4096);
  transpose_kernel<1><<<dim3(32, 128, 8), blk, 0, stream>>>(W2, W2T, nullptr, 4096, 1024);
  wg_transpose<<<dim3(32), blk, 0, stream>>>(Wg, WgT);
  // LN1 -> h (f16 hi/lo)
  ln_kernel<<<dim3(4096), blk, 0, stream>>>(x, ln1g, ln1b, hh, hl);
  // QKV = h @ Wqkv (split-f16 x3, 512 thr) -> f32
  gemm_kernel<0><<<dim3(24, 32), blk512, 0, stream>>>(hh, hl, WqkvTh, WqkvTl, 1024, 3072, 0,
                                                      nullptr, nullptr, nullptr, nullptr,
                                                      qkv, nullptr, nullptr, nullptr);
  // K/V pre-convert to split-f16 planes
  kv_prep<<<dim3(16, 16, 4), blk, 0, stream>>>(qkv, Kh, Kl, Vth, Vtl);
  // flash attention (balanced causal pairing: each block does 17 tile-steps)
  attn_kernel<<<dim3(8, 16, 4), blk, 0, stream>>>(qkv, Kh, Kl, Vth, Vtl, atth, attl);
  // x_resid = x + attn @ Wo (split-f16 x3, TN=64, 512 thr) -> d_out
  gemm_kernel<1><<<dim3(16, 32), blk512, 0, stream>>>(atth, attl, WoTh, WoTl, 1024, 1024, 0,
                                                      nullptr, nullptr, nullptr, nullptr,
                                                      out, nullptr, x, nullptr);
  // routing (f32, WgT coalesced, no atomics) + fused LN2 -> moein
  gate_kernel<<<dim3(1024), blk, 0, stream>>>(out, ln2g, ln2b, WgT, tok_e, tok_w, moein);
  // plan: histogram tok_e + tile table + cursor init (single block)
  plan_kernel<<<dim3(1), blk, 0, stream>>>(tok_e, cursor, tile_e, tile_b, tile_c);
  // scatter: deterministic per-expert ballot-scan compaction (grid 8, no atomics)
  scatter_kernel<<<dim3(8), blk, 0, stream>>>(tok_e, tok_w, cursor, lists, slotw);
  // FFN1: gather tokens, gelu(h @ W1[e]) -> act bf16 (TN=128, XCD-chunked, 512 thr)
  gemm_kernel<2><<<dim3(8 * 9 * 32), blk512, 0, stream>>>(moein, nullptr, W1T, nullptr, 1024, 4096, 4096,
                                                          lists, tile_e, tile_b, tile_c,
                                                          nullptr, act, nullptr, nullptr);
  // FFN2: act @ W2[e] * gate -> ypart scatter (TN=128, XCD-chunked, 512 thr)
  gemm_kernel<3><<<dim3(8 * 9 * 8), blk512, 0, stream>>>(act, nullptr, W2T, nullptr, 4096, 1024, 1024,
                                                         lists, tile_e, tile_b, tile_c,
                                                         ypart, nullptr, nullptr, slotw);
  // out = x_resid + y0 + y1
  combine_kernel<<<dim3(4096), blk, 0, stream>>>(out, ypart);
}

// Round 15
// 529.726 us; speedup vs baseline: 1.0951x; 1.0018x over previous
//
#include <hip/hip_runtime.h>

// B=4 S=1024 D=1024 H=16 HD=64 E=8 TOPK=2 F=4096 ; tokens N=4096
typedef unsigned short u16;
typedef _Float16 f16x8 __attribute__((ext_vector_type(8)));
typedef __bf16   bf16x8 __attribute__((ext_vector_type(8)));
typedef float    f32x4 __attribute__((ext_vector_type(4)));

struct __align__(8) U16x4 { u16 v[4]; };

#define MAXT 72

__device__ __forceinline__ u16 f2b(float f) {            // f32 -> bf16 RNE bits
  unsigned u = __builtin_bit_cast(unsigned, f);
  return (u16)((u + 0x7FFFu + ((u >> 16) & 1u)) >> 16);
}
__device__ __forceinline__ u16 f2h(float f) { return __builtin_bit_cast(u16, (_Float16)f); }
__device__ __forceinline__ u16 f2h_lo(float f) {
  _Float16 h = (_Float16)f;
  return __builtin_bit_cast(u16, (_Float16)(f - (float)h));
}
__device__ __forceinline__ void llds16(const void* g, void* l) {
  __builtin_amdgcn_global_load_lds((const __attribute__((address_space(1))) unsigned int*)g,
                                   (__attribute__((address_space(3))) unsigned int*)l, 16, 0, 0);
}
__device__ __forceinline__ f32x4 mmf(f16x8 a, f16x8 b, f32x4 c) {
  return __builtin_amdgcn_mfma_f32_16x16x32_f16(a, b, c, 0, 0, 0);
}
__device__ __forceinline__ f32x4 mmb(bf16x8 a, bf16x8 b, f32x4 c) {
  return __builtin_amdgcn_mfma_f32_16x16x32_bf16(a, b, c, 0, 0, 0);
}

// ---------------- transpose + convert: src [R,C] f32 -> dst [C,R] f16(hi/lo) or bf16 ----
template<int OUT> // 0: f16 split pair, 1: bf16 single
__global__ __launch_bounds__(256) void transpose_kernel(const float* __restrict__ src,
                                                        u16* __restrict__ d0, u16* __restrict__ d1,
                                                        int R, int C) {
  __shared__ float t[32][33];
  long zo = (long)blockIdx.z * R * C;
  int r0 = blockIdx.y << 5, c0 = blockIdx.x << 5;
  int tid = threadIdx.x;
  {
    int r = tid >> 3, c = (tid & 7) << 2;
    float4 v = *(const float4*)(src + zo + (long)(r0 + r) * C + c0 + c);
    t[r][c] = v.x; t[r][c + 1] = v.y; t[r][c + 2] = v.z; t[r][c + 3] = v.w;
  }
  __syncthreads();
  int c = tid >> 3, rg = (tid & 7) << 2;
  long o = zo + (long)(c0 + c) * R + r0 + rg;
  U16x4 a, b2;
#pragma unroll
  for (int i = 0; i < 4; i++) {
    float f = t[rg + i][c];
    if (OUT == 0) { a.v[i] = f2h(f); b2.v[i] = f2h_lo(f); }
    else a.v[i] = f2b(f);
  }
  *(U16x4*)(d0 + o) = a;
  if (OUT == 0) *(U16x4*)(d1 + o) = b2;
}

// ---------------- Wg [1024,8] -> WgT [8,1024] (tiny, for coalesced gate loads) ---------
__global__ __launch_bounds__(256) void wg_transpose(const float* __restrict__ Wg,
                                                    float* __restrict__ WgT) {
  int idx = blockIdx.x * 256 + threadIdx.x;   // 8192 elements
  int d = idx >> 3, e = idx & 7;
  WgT[e * 1024 + d] = Wg[idx];
}

// ---------------- LayerNorm row kernel (LN1 only; LN2 fused into gate) ----------------
__global__ __launch_bounds__(256) void ln_kernel(const float* __restrict__ x, const float* __restrict__ g,
                                                 const float* __restrict__ bt,
                                                 u16* __restrict__ d0, u16* __restrict__ d1) {
  long row = blockIdx.x;
  int tid = threadIdx.x;
  const float4 v = *(const float4*)(x + (row << 10) + (tid << 2));
  float s = v.x + v.y + v.z + v.w;
  float q = v.x * v.x + v.y * v.y + v.z * v.z + v.w * v.w;
#pragma unroll
  for (int m = 1; m < 64; m <<= 1) { s += __shfl_xor(s, m); q += __shfl_xor(q, m); }
  __shared__ float rs[4], rq[4];
  if ((tid & 63) == 0) { rs[tid >> 6] = s; rq[tid >> 6] = q; }
  __syncthreads();
  s = rs[0] + rs[1] + rs[2] + rs[3];
  q = rq[0] + rq[1] + rq[2] + rq[3];
  float mu = s * (1.f / 1024.f);
  float inv = 1.f / sqrtf(q * (1.f / 1024.f) - mu * mu + 1e-5f);
  float4 gg = *(const float4*)(g + (tid << 2));
  float4 bb = *(const float4*)(bt + (tid << 2));
  float o0 = (v.x - mu) * inv * gg.x + bb.x;
  float o1 = (v.y - mu) * inv * gg.y + bb.y;
  float o2 = (v.z - mu) * inv * gg.z + bb.z;
  float o3 = (v.w - mu) * inv * gg.w + bb.w;
  long o = (row << 10) + (tid << 2);
  U16x4 a, b2;
  a.v[0] = f2h(o0); a.v[1] = f2h(o1); a.v[2] = f2h(o2); a.v[3] = f2h(o3);
  b2.v[0] = f2h_lo(o0); b2.v[1] = f2h_lo(o1); b2.v[2] = f2h_lo(o2); b2.v[3] = f2h_lo(o3);
  *(U16x4*)(d0 + o) = a; *(U16x4*)(d1 + o) = b2;
}

// ------- unified tiled GEMM, 128xTN xK BK=64, A[M,K] x Bt[N,K], 512 thr / 8 waves -------
// Wave grid 2x4: wave covers 64 x (TN/4) of the tile (acc[4][NF], NF = TN/64).
// MODE 0: split f16 x3 -> f32 out (QKV), TN=128, single-buffered (64KB).
// MODE 1: split f16 x3 -> f32 + resid (Wo), TN=64, single-buffered.
// MODE 2: bf16, A gathered via lists -> gelu -> bf16 (FFN1), TN=128, XCD-chunked, 32KB.
// MODE 3: bf16, A direct grouped -> scatter f32 w*acc (FFN2), TN=128, XCD-chunked, 32KB.
// NOTE: this 2-barrier 128x128/32KB config is the measured local optimum for this
// shape family (R5/R7/R11/R12/R13 all regressed vs it) — frozen.
template<int MODE>
__global__ __launch_bounds__(512, 1) void gemm_kernel(
    const u16* __restrict__ Ah, const u16* __restrict__ Al,
    const u16* __restrict__ Bh, const u16* __restrict__ Bl,
    int K, int ldc, int Nexp,
    const int* __restrict__ lists, const int* __restrict__ tile_e,
    const int* __restrict__ tile_b, const int* __restrict__ tile_c,
    float* __restrict__ outf, u16* __restrict__ outb,
    const float* __restrict__ resid, const float* __restrict__ slotw) {
  constexpr bool SPLIT = (MODE < 2);
  constexpr int TN = (MODE == 1) ? 64 : 128;   // tile N
  constexpr int NF = TN >> 6;                  // n-frags per wave (2 or 1)
  constexpr int NB = TN >> 6;                  // B staging chunks per thread (2 or 1)
  constexpr int SMEM = SPLIT ? 65536 : 32768;
  __shared__ __align__(16) char smem[SMEM];
  char* pAh = smem;
  char* pBh = smem + 16384;
  char* pAl = smem + 32768;   // SPLIT only
  char* pBl = smem + 49152;   // SPLIT only
  const int tid = threadIdx.x, w = tid >> 6, l = tid & 63;
  int n0;
  int grbase = 0, rowsv = 128;
  long m0 = 0;
  if (MODE >= 2) {
    // Chunked XCD swizzle: XCD c owns 9 consecutive y-tiles (A-panel sharers colocate
    // on one L2; an expert's tiles stay mostly within one XCD for W reuse).
    int lin = blockIdx.x;
    int c = lin & 7, k = lin >> 3;
    int ty = c * 9 + (k % 9);      // tile index [0,72)
    int tx = k / 9;                // n-tile
    n0 = tx * TN;
    int e = tile_e[ty];
    if (e < 0) return;
    grbase = tile_b[ty];
    rowsv = tile_c[ty];
    Bh += (long)e * Nexp * K;
  } else {
    n0 = blockIdx.x * TN;
    m0 = (long)blockIdx.y << 7;
  }

  const u16 *as0[2], *as1[2], *bs0[2], *bs1[2];
  int dstA[2], dstB[2];
#pragma unroll
  for (int i = 0; i < 2; i++) {        // A: 1024 chunks of 16B over 512 threads
    int chunk = i * 512 + tid;
    int row = chunk >> 3, c16 = chunk & 7;
    int scol = (c16 << 4) ^ ((row & 7) << 4);   // pre-swizzled source byte col
    dstA[i] = chunk << 4;
    long ar;
    if (MODE == 2) {
      int vlu = lists[(row < rowsv) ? (grbase + row) : grbase];
      ar = (long)(vlu >> 1);
    } else if (MODE == 3) {
      ar = grbase + ((row < rowsv) ? row : 0);
    } else {
      ar = m0 + row;
    }
    long ao = ar * (long)K + (scol >> 1);
    as0[i] = Ah + ao;
    if (SPLIT) as1[i] = Al + ao;
  }
#pragma unroll
  for (int i = 0; i < NB; i++) {       // B: TN*8 chunks of 16B over 512 threads
    int chunk = i * 512 + tid;
    int row = chunk >> 3, c16 = chunk & 7;
    int scol = (c16 << 4) ^ ((row & 7) << 4);
    dstB[i] = chunk << 4;
    long bo = (long)(n0 + row) * K + (scol >> 1);
    bs0[i] = Bh + bo;
    if (SPLIT) bs1[i] = Bl + bo;
  }

  f32x4 acc[4][NF];
#pragma unroll
  for (int i = 0; i < 4; i++)
#pragma unroll
    for (int j = 0; j < NF; j++) acc[i][j] = (f32x4){0.f, 0.f, 0.f, 0.f};

  const int wr = (w >> 2) << 6;            // wave-row: 2 rows of 64
  const int wc = (w & 3) * (TN / 4);       // wave-col: 4 cols of TN/4
  const int nkt = K >> 6;
  for (int kt = 0; kt < nkt; ++kt) {
    if (kt) __syncthreads();
#pragma unroll
    for (int i = 0; i < 2; i++) {
      llds16(as0[i] + (kt << 6), pAh + dstA[i]);
      if (SPLIT) llds16(as1[i] + (kt << 6), pAl + dstA[i]);
    }
#pragma unroll
    for (int i = 0; i < NB; i++) {
      llds16(bs0[i] + (kt << 6), pBh + dstB[i]);
      if (SPLIT) llds16(bs1[i] + (kt << 6), pBl + dstB[i]);
    }
    __syncthreads();
#pragma unroll
    for (int kc = 0; kc < 2; kc++) {
      const int kby = (kc << 6) + ((l >> 4) << 4);
      int aoff[4], boff[NF];
#pragma unroll
      for (int mf = 0; mf < 4; mf++) { int row = wr + (mf << 4) + (l & 15); aoff[mf] = (row << 7) + (kby ^ ((row & 7) << 4)); }
#pragma unroll
      for (int nf = 0; nf < NF; nf++) { int row = wc + (nf << 4) + (l & 15); boff[nf] = (row << 7) + (kby ^ ((row & 7) << 4)); }
      if (SPLIT) {
        f16x8 a0[4], a1[4], b0[NF], b1[NF];
#pragma unroll
        for (int mf = 0; mf < 4; mf++) {
          a0[mf] = *(const f16x8*)(pAh + aoff[mf]);
          a1[mf] = *(const f16x8*)(pAl + aoff[mf]);
        }
#pragma unroll
        for (int nf = 0; nf < NF; nf++) {
          b0[nf] = *(const f16x8*)(pBh + boff[nf]);
          b1[nf] = *(const f16x8*)(pBl + boff[nf]);
        }
#pragma unroll
        for (int mf = 0; mf < 4; mf++)
#pragma unroll
          for (int nf = 0; nf < NF; nf++) {
            acc[mf][nf] = mmf(a0[mf], b0[nf], acc[mf][nf]);
            acc[mf][nf] = mmf(a0[mf], b1[nf], acc[mf][nf]);
            acc[mf][nf] = mmf(a1[mf], b0[nf], acc[mf][nf]);
          }
      } else {
        bf16x8 a0[4], b0[NF];
#pragma unroll
        for (int mf = 0; mf < 4; mf++) a0[mf] = *(const bf16x8*)(pAh + aoff[mf]);
#pragma unroll
        for (int nf = 0; nf < NF; nf++) b0[nf] = *(const bf16x8*)(pBh + boff[nf]);
#pragma unroll
        for (int mf = 0; mf < 4; mf++)
#pragma unroll
          for (int nf = 0; nf < NF; nf++) acc[mf][nf] = mmb(a0[mf], b0[nf], acc[mf][nf]);
      }
    }
  }

  // epilogue: C/D layout col = lane&15, row = (lane>>4)*4 + reg
#pragma unroll
  for (int mf = 0; mf < 4; mf++) {
#pragma unroll
    for (int r = 0; r < 4; r++) {
      const int lrow = wr + (mf << 4) + ((l >> 4) << 2) + r;
      if (MODE >= 2 && lrow >= rowsv) continue;
      float gw = 0.f; long orow = 0;
      if (MODE == 3) { int gr = grbase + lrow; orow = (long)lists[gr] * ldc; gw = slotw[gr]; }
#pragma unroll
      for (int nf = 0; nf < NF; nf++) {
        const int col = n0 + wc + (nf << 4) + (l & 15);
        float v = acc[mf][nf][r];
        if (MODE == 0) {
          outf[(m0 + lrow) * (long)ldc + col] = v;
        } else if (MODE == 1) {
          long ix = (m0 + lrow) * (long)ldc + col;
          outf[ix] = v + resid[ix];
        } else if (MODE == 2) {
          // gelu(v) = v * sigmoid(1.5957691 v + 0.0713549 v^3)  (exact tanh-form identity)
          float t = v * (1.59576912f + 0.07135539f * v * v);
          float u = v * __builtin_amdgcn_rcpf(1.f + __expf(-t));
          outb[(long)(grbase + lrow) * ldc + col] = f2b(u);
        } else {
          outf[orow + col] = v * gw;
        }
      }
    }
  }
}

// ---------------- K/V pre-convert: per (b,h) planes Kh/Kl [1024][64], Vth/Vtl [64][1024] ----
__global__ __launch_bounds__(256) void kv_prep(const float* __restrict__ qkv,
                                               u16* __restrict__ Kh, u16* __restrict__ Kl,
                                               u16* __restrict__ Vth, u16* __restrict__ Vtl) {
  __shared__ float t[64][65];
  const int tid = threadIdx.x;
  const int kb = blockIdx.x, h = blockIdx.y, b = blockIdx.z;
  const long bb = ((long)b) << 10;
  const int hoff = h << 6;
  const long head = ((long)(b * 16 + h)) << 16;   // 65536 elems per head-plane
  {
    int rr = tid >> 4, c = (tid & 15) << 2;
#pragma unroll
    for (int p = 0; p < 4; p++) {
      int r = rr + p * 16;
      const float* base = qkv + (bb + kb * 64 + r) * 3072 + hoff + c;
      float4 u = *(const float4*)(base + 1024);
      U16x4 a, lo;
      a.v[0] = f2h(u.x); a.v[1] = f2h(u.y); a.v[2] = f2h(u.z); a.v[3] = f2h(u.w);
      lo.v[0] = f2h_lo(u.x); lo.v[1] = f2h_lo(u.y); lo.v[2] = f2h_lo(u.z); lo.v[3] = f2h_lo(u.w);
      long o = head + (long)(kb * 64 + r) * 64 + c;
      *(U16x4*)(Kh + o) = a; *(U16x4*)(Kl + o) = lo;
      float4 v = *(const float4*)(base + 2048);
      t[r][c] = v.x; t[r][c + 1] = v.y; t[r][c + 2] = v.z; t[r][c + 3] = v.w;
    }
  }
  __syncthreads();
  {
    int hd = tid >> 2, k4 = (tid & 3) << 4;
#pragma unroll
    for (int q = 0; q < 4; q++) {
      U16x4 a, lo;
#pragma unroll
      for (int j = 0; j < 4; j++) {
        float f = t[k4 + q * 4 + j][hd];
        a.v[j] = f2h(f); lo.v[j] = f2h_lo(f);
      }
      long o = head + (long)hd * 1024 + kb * 64 + k4 + q * 4;
      *(U16x4*)(Vth + o) = a; *(U16x4*)(Vtl + o) = lo;
    }
  }
}

// ---------------- flash attention v3: prepped K/V planes, llds staging, balanced pairing,
// s_setprio around MFMA clusters (m191: positive in independent-block attn regime),
// rcp instead of per-element divide in the O normalization ----
__global__ __launch_bounds__(256, 1) void attn_kernel(const float* __restrict__ qkv,
                                                      const u16* __restrict__ Kh, const u16* __restrict__ Kl,
                                                      const u16* __restrict__ Vth, const u16* __restrict__ Vtl,
                                                      u16* __restrict__ oh, u16* __restrict__ ol) {
  __shared__ u16 kh[4096], kl[4096];       // K tile [64 key][64 hd], swizzled
  __shared__ u16 vh[4096], vl[4096];       // V^T tile [64 hd][64 key], swizzled
  __shared__ u16 ph[4][1024], pl[4][1024]; // per-wave P [16 m][64 k]
  const int tid = threadIdx.x, w = tid >> 6, l = tid & 63;
  const int qbi = blockIdx.x, hh_ = blockIdx.y, b = blockIdx.z;
  const long bb = ((long)b) << 10;
  const int hoff = hh_ << 6;
  const long head = ((long)(b * 16 + hh_)) << 16;

  // staging descriptors (2 chunks of 16B per thread per plane)
  const u16 *ks0[2], *ks1[2], *vs0[2], *vs1[2];
  int db[2];
#pragma unroll
  for (int i = 0; i < 2; i++) {
    int chunk = i * 256 + tid;
    int row = chunk >> 3, c16 = chunk & 7;
    int sc = ((c16 << 4) ^ ((row & 7) << 4)) >> 1;
    db[i] = chunk << 4;
    ks0[i] = Kh + head + row * 64 + sc;
    ks1[i] = Kl + head + row * 64 + sc;
    vs0[i] = Vth + head + (long)row * 1024 + sc;
    vs1[i] = Vtl + head + (long)row * 1024 + sc;
  }

  for (int pass = 0; pass < 2; ++pass) {
    const int qb = (pass ? qbi : (15 - qbi)) << 6;   // long pass first; total 17 tiles/block
    // load Q fragments (split f16)
    f16x8 q0[2], q1[2];
    {
      const long qrow = bb + qb + (w << 4) + (l & 15);
      const float* qp = qkv + qrow * 3072 + hoff + ((l >> 4) << 3);
#pragma unroll
      for (int kc = 0; kc < 2; kc++) {
        float4 u0 = *(const float4*)(qp + (kc << 5));
        float4 u1 = *(const float4*)(qp + (kc << 5) + 4);
        float vv[8] = {u0.x, u0.y, u0.z, u0.w, u1.x, u1.y, u1.z, u1.w};
#pragma unroll
        for (int j = 0; j < 8; j++) {
          _Float16 hi = (_Float16)vv[j];
          q0[kc][j] = hi;
          q1[kc][j] = (_Float16)(vv[j] - (float)hi);
        }
      }
    }

    f32x4 o[4];
#pragma unroll
    for (int nf = 0; nf < 4; nf++) o[nf] = (f32x4){0.f, 0.f, 0.f, 0.f};
    float mr[4] = {-1e30f, -1e30f, -1e30f, -1e30f};
    float lr[4] = {0.f, 0.f, 0.f, 0.f};
    const int ktm = qb >> 6;

    for (int kt = 0; kt <= ktm; ++kt) {
      __syncthreads();
#pragma unroll
      for (int i = 0; i < 2; i++) {
        llds16(ks0[i] + (kt << 12), (char*)kh + db[i]);
        llds16(ks1[i] + (kt << 12), (char*)kl + db[i]);
        llds16(vs0[i] + (kt << 6), (char*)vh + db[i]);
        llds16(vs1[i] + (kt << 6), (char*)vl + db[i]);
      }
      __syncthreads();

      // QK^T (split x3)
      f32x4 s[4];
#pragma unroll
      for (int nf = 0; nf < 4; nf++) s[nf] = (f32x4){0.f, 0.f, 0.f, 0.f};
      __builtin_amdgcn_s_setprio(1);
#pragma unroll
      for (int kc = 0; kc < 2; kc++) {
        const int kby = (kc << 6) + ((l >> 4) << 4);
#pragma unroll
        for (int nf = 0; nf < 4; nf++) {
          int row = (nf << 4) + (l & 15);
          int off = (row << 7) + (kby ^ ((row & 7) << 4));
          f16x8 k0 = *(const f16x8*)((const char*)kh + off);
          f16x8 k1 = *(const f16x8*)((const char*)kl + off);
          s[nf] = mmf(q0[kc], k0, s[nf]);
          s[nf] = mmf(q0[kc], k1, s[nf]);
          s[nf] = mmf(q1[kc], k0, s[nf]);
        }
      }
      __builtin_amdgcn_s_setprio(0);
      const bool lastt = (kt == ktm);
#pragma unroll
      for (int nf = 0; nf < 4; nf++)
#pragma unroll
        for (int r = 0; r < 4; r++) {
          float sc = s[nf][r] * 0.125f;
          if (lastt) {
            int keyg = (kt << 6) + (nf << 4) + (l & 15);
            int qg = qb + (w << 4) + ((l >> 4) << 2) + r;
            if (keyg > qg) sc = -1e30f;
          }
          s[nf][r] = sc;
        }
      float alpha[4];
#pragma unroll
      for (int r = 0; r < 4; r++) {
        float mx = fmaxf(fmaxf(s[0][r], s[1][r]), fmaxf(s[2][r], s[3][r]));
        mx = fmaxf(mx, __shfl_xor(mx, 1));
        mx = fmaxf(mx, __shfl_xor(mx, 2));
        mx = fmaxf(mx, __shfl_xor(mx, 4));
        mx = fmaxf(mx, __shfl_xor(mx, 8));
        float mn = fmaxf(mr[r], mx);
        float su = 0.f;
#pragma unroll
        for (int nf = 0; nf < 4; nf++) { float pv = __expf(s[nf][r] - mn); s[nf][r] = pv; su += pv; }
        su += __shfl_xor(su, 1); su += __shfl_xor(su, 2);
        su += __shfl_xor(su, 4); su += __shfl_xor(su, 8);
        alpha[r] = __expf(mr[r] - mn);
        lr[r] = lr[r] * alpha[r] + su;
        mr[r] = mn;
      }
#pragma unroll
      for (int nf = 0; nf < 4; nf++)
#pragma unroll
        for (int r = 0; r < 4; r++) o[nf][r] *= alpha[r];
      // write P (hi/lo) to per-wave LDS
#pragma unroll
      for (int nf = 0; nf < 4; nf++)
#pragma unroll
        for (int r = 0; r < 4; r++) {
          int m = ((l >> 4) << 2) + r, k = (nf << 4) + (l & 15);
          int off = (m << 7) + ((k << 1) ^ ((m & 7) << 4));
          float pv = s[nf][r];
          _Float16 hi = (_Float16)pv;
          *(u16*)((char*)&ph[w][0] + off) = __builtin_bit_cast(u16, hi);
          *(u16*)((char*)&pl[w][0] + off) = __builtin_bit_cast(u16, (_Float16)(pv - (float)hi));
        }
      // PV (split x3)
      __builtin_amdgcn_s_setprio(1);
#pragma unroll
      for (int kc = 0; kc < 2; kc++) {
        const int kby = (kc << 6) + ((l >> 4) << 4);
        const int mm = l & 15;
        int poff = (mm << 7) + (kby ^ ((mm & 7) << 4));
        f16x8 p0 = *(const f16x8*)((const char*)&ph[w][0] + poff);
        f16x8 p1 = *(const f16x8*)((const char*)&pl[w][0] + poff);
#pragma unroll
        for (int nf = 0; nf < 4; nf++) {
          int row = (nf << 4) + (l & 15);
          int off = (row << 7) + (kby ^ ((row & 7) << 4));
          f16x8 v0 = *(const f16x8*)((const char*)vh + off);
          f16x8 v1 = *(const f16x8*)((const char*)vl + off);
          o[nf] = mmf(p0, v0, o[nf]);
          o[nf] = mmf(p0, v1, o[nf]);
          o[nf] = mmf(p1, v0, o[nf]);
        }
      }
      __builtin_amdgcn_s_setprio(0);
    }
    // store O split to f16 planes (rcp: 4 per-row reciprocals instead of 16 divides;
    // 1-ulp rcp error << split-f16 22-bit representation error -> routing-safe)
    float il[4];
#pragma unroll
    for (int r = 0; r < 4; r++) il[r] = __builtin_amdgcn_rcpf(lr[r]);
#pragma unroll
    for (int nf = 0; nf < 4; nf++)
#pragma unroll
      for (int r = 0; r < 4; r++) {
        int lrow = (w << 4) + ((l >> 4) << 2) + r;
        float v = o[nf][r] * il[r];
        long ix = (bb + qb + lrow) * 1024 + hoff + (nf << 4) + (l & 15);
        _Float16 hi = (_Float16)v;
        oh[ix] = __builtin_bit_cast(u16, hi);
        ol[ix] = __builtin_bit_cast(u16, (_Float16)(v - (float)hi));
      }
  }
}

// ------- gating v2: f32 LN + logits (WgT coalesced) + top2, fused LN2 out, NO atomics ----
__global__ __launch_bounds__(256) void gate_kernel(const float* __restrict__ xr, const float* __restrict__ g,
                                                   const float* __restrict__ b, const float* __restrict__ WgT,
                                                   int* __restrict__ tok_e, float* __restrict__ tok_w,
                                                   u16* __restrict__ moe) {
  int w = threadIdx.x >> 6, l = threadIdx.x & 63;
  long t = (long)blockIdx.x * 4 + w;
  const float* row = xr + (t << 10);
  float4 xv[4]; float s = 0.f, q = 0.f;
#pragma unroll
  for (int i = 0; i < 4; i++) {
    float4 v = *(const float4*)(row + (i << 8) + (l << 2));
    xv[i] = v;
    s += v.x + v.y + v.z + v.w;
    q += v.x * v.x + v.y * v.y + v.z * v.z + v.w * v.w;
  }
#pragma unroll
  for (int m = 1; m < 64; m <<= 1) { s += __shfl_xor(s, m); q += __shfl_xor(q, m); }
  float mu = s * (1.f / 1024.f);
  float inv = 1.f / sqrtf(q * (1.f / 1024.f) - mu * mu + 1e-5f);
  float acc[8] = {0.f, 0.f, 0.f, 0.f, 0.f, 0.f, 0.f, 0.f};
#pragma unroll
  for (int i = 0; i < 4; i++) {
    int d0 = (i << 8) + (l << 2);
    float4 gg = *(const float4*)(g + d0);
    float4 bb = *(const float4*)(b + d0);
    float x0 = (xv[i].x - mu) * inv * gg.x + bb.x;
    float x1 = (xv[i].y - mu) * inv * gg.y + bb.y;
    float x2 = (xv[i].z - mu) * inv * gg.z + bb.z;
    float x3 = (xv[i].w - mu) * inv * gg.w + bb.w;
    U16x4 st;
    st.v[0] = f2b(x0); st.v[1] = f2b(x1); st.v[2] = f2b(x2); st.v[3] = f2b(x3);
    *(U16x4*)(moe + (t << 10) + d0) = st;
#pragma unroll
    for (int e = 0; e < 8; e++) {
      float4 wq = *(const float4*)(WgT + (e << 10) + d0);
      acc[e] += x0 * wq.x + x1 * wq.y + x2 * wq.z + x3 * wq.w;
    }
  }
#pragma unroll
  for (int e = 0; e < 8; e++)
#pragma unroll
    for (int m = 1; m < 64; m <<= 1) acc[e] += __shfl_xor(acc[e], m);
  if (l == 0) {
    int e0 = 0; float v0 = acc[0];
#pragma unroll
    for (int e = 1; e < 8; e++) if (acc[e] > v0) { v0 = acc[e]; e0 = e; }
    int e1 = (e0 == 0) ? 1 : 0; float v1 = acc[e1];
#pragma unroll
    for (int e = 0; e < 8; e++) if (e != e0 && acc[e] > v1) { v1 = acc[e]; e1 = e; }
    float w0 = 1.f / (1.f + __expf(v1 - v0));
    tok_e[t * 2] = e0; tok_e[t * 2 + 1] = e1;
    tok_w[t * 2] = w0; tok_w[t * 2 + 1] = 1.f - w0;
  }
}

// ------- plan v2: 256-thread histogram of tok_e (named counters + shuffle reduce) -------
__global__ __launch_bounds__(256) void plan_kernel(const int* __restrict__ tok_e, int* __restrict__ cursor,
                                                   int* __restrict__ tile_e, int* __restrict__ tile_b,
                                                   int* __restrict__ tile_c) {
  __shared__ int wc[4][8];
  int tid = threadIdx.x, w = tid >> 6, l = tid & 63;
  int c0 = 0, c1 = 0, c2 = 0, c3 = 0, c4 = 0, c5 = 0, c6 = 0, c7 = 0;
  for (int k = 0; k < 32; k++) {
    int v = tok_e[(w << 11) + (k << 6) + l];
    c0 += (v == 0); c1 += (v == 1); c2 += (v == 2); c3 += (v == 3);
    c4 += (v == 4); c5 += (v == 5); c6 += (v == 6); c7 += (v == 7);
  }
#pragma unroll
  for (int m = 1; m < 64; m <<= 1) {
    c0 += __shfl_xor(c0, m); c1 += __shfl_xor(c1, m); c2 += __shfl_xor(c2, m); c3 += __shfl_xor(c3, m);
    c4 += __shfl_xor(c4, m); c5 += __shfl_xor(c5, m); c6 += __shfl_xor(c6, m); c7 += __shfl_xor(c7, m);
  }
  if (l == 0) {
    wc[w][0] = c0; wc[w][1] = c1; wc[w][2] = c2; wc[w][3] = c3;
    wc[w][4] = c4; wc[w][5] = c5; wc[w][6] = c6; wc[w][7] = c7;
  }
  __syncthreads();
  if (tid == 0) {
    int o = 0, t2 = 0;
    for (int e = 0; e < 8; e++) {
      cursor[e] = o;
      int cc = wc[0][e] + wc[1][e] + wc[2][e] + wc[3][e];
      for (int i = 0; i < cc; i += 128) {
        tile_e[t2] = e; tile_b[t2] = o + i; tile_c[t2] = (cc - i < 128) ? (cc - i) : 128; t2++;
      }
      o += cc;
    }
    for (; t2 < MAXT; t2++) tile_e[t2] = -1;
  }
}

// ------- scatter v2: deterministic ballot-scan compaction, NO atomics ---------------------
// Block e compacts all slots with tok_e[slot]==e in ascending slot order.
__global__ __launch_bounds__(256) void scatter_kernel(const int* __restrict__ tok_e,
                                                      const float* __restrict__ tok_w,
                                                      const int* __restrict__ cursor,
                                                      int* __restrict__ lists,
                                                      float* __restrict__ slotw) {
  const int e = blockIdx.x;
  const int tid = threadIdx.x, w = tid >> 6, l = tid & 63;
  __shared__ int wbase[4];
  __shared__ int running;
  if (tid == 0) running = cursor[e];
  __syncthreads();
  for (int base = 0; base < 8192; base += 256) {
    int slot = base + tid;
    bool m = (tok_e[slot] == e);
    unsigned long long mask = __ballot(m);
    int prefix = __popcll(mask & ((1ull << l) - 1ull));
    if (l == 0) wbase[w] = __popcll(mask);
    __syncthreads();
    int off = running + prefix;
#pragma unroll
    for (int i = 0; i < 3; i++) if (w > i) off += wbase[i];
    if (m) { lists[off] = slot; slotw[off] = tok_w[slot]; }
    int total = wbase[0] + wbase[1] + wbase[2] + wbase[3];
    __syncthreads();
    if (tid == 0) running += total;
    __syncthreads();
  }
}

__global__ __launch_bounds__(256) void combine_kernel(float* __restrict__ out, const float* __restrict__ yp) {
  long i = (long)blockIdx.x * 256 + threadIdx.x;  // float4 index over 4M floats
  long n = i >> 8;
  long d = i & 255;
  float4 o = *(float4*)(out + (i << 2));
  const float4 a = *(const float4*)(yp + ((n * 2) << 10) + (d << 2));
  const float4 b = *(const float4*)(yp + ((n * 2 + 1) << 10) + (d << 2));
  o.x += a.x + b.x; o.y += a.y + b.y; o.z += a.z + b.z; o.w += a.w + b.w;
  *(float4*)(out + (i << 2)) = o;
}

extern "C" void kernel_launch(void* const* d_in, const int* in_sizes, int n_in,
                              void* d_out, int out_size, void* d_ws, size_t ws_size,
                              hipStream_t stream) {
  const float* x    = (const float*)d_in[0];
  const float* ln1g = (const float*)d_in[1];
  const float* ln1b = (const float*)d_in[2];
  const float* Wqkv = (const float*)d_in[3];
  const float* Wo   = (const float*)d_in[4];
  const float* ln2g = (const float*)d_in[5];
  const float* ln2b = (const float*)d_in[6];
  const float* Wg   = (const float*)d_in[7];
  const float* W1   = (const float*)d_in[8];
  const float* W2   = (const float*)d_in[9];
  float* out = (float*)d_out;
  char* ws = (char*)d_ws;

  size_t off = 0;
  auto alloc = [&](size_t b) { size_t o = off; off += (b + 255) & ~size_t(255); return o; };
  u16* WqkvTh = (u16*)(ws + alloc(3072ull * 1024 * 2));
  u16* WqkvTl = (u16*)(ws + alloc(3072ull * 1024 * 2));
  u16* WoTh   = (u16*)(ws + alloc(1024ull * 1024 * 2));
  u16* WoTl   = (u16*)(ws + alloc(1024ull * 1024 * 2));
  u16* W1T    = (u16*)(ws + alloc(8ull * 4096 * 1024 * 2));
  u16* W2T    = (u16*)(ws + alloc(8ull * 1024 * 4096 * 2));
  u16* hh     = (u16*)(ws + alloc(4096ull * 1024 * 2));
  u16* hl     = (u16*)(ws + alloc(4096ull * 1024 * 2));
  float* qkv  = (float*)(ws + alloc(4096ull * 3072 * 4));
  u16* atth   = (u16*)(ws + alloc(4096ull * 1024 * 2));
  u16* attl   = (u16*)(ws + alloc(4096ull * 1024 * 2));
  u16* moein  = (u16*)(ws + alloc(4096ull * 1024 * 2));
  u16* act    = (u16*)(ws + alloc(8192ull * 4096 * 2));
  float* WgT  = (float*)(ws + alloc(8ull * 1024 * 4));
  float* ypart = qkv;  // alias: qkv (50.3MB) dead after attention; ypart needs 33.6MB
  // K/V f16 planes alias into act (dead until FFN1): 4 planes x 8MB = 32MB < 67MB
  u16* Kh  = act;
  u16* Kl  = act + 4194304;
  u16* Vth = act + 2 * 4194304;
  u16* Vtl = act + 3 * 4194304;
  int* tok_e  = (int*)(ws + alloc(8192 * 4));
  float* tok_w = (float*)(ws + alloc(8192 * 4));
  int* cursor = (int*)(ws + alloc(64));
  int* lists  = (int*)(ws + alloc(8192 * 4));
  float* slotw = (float*)(ws + alloc(8192 * 4));
  int* tile_e = (int*)(ws + alloc(MAXT * 4));
  int* tile_b = (int*)(ws + alloc(MAXT * 4));
  int* tile_c = (int*)(ws + alloc(MAXT * 4));
  (void)in_sizes; (void)n_in; (void)out_size; (void)ws_size;

  dim3 blk(256), blk512(512);
  // weight transpose+convert (B^T layout for all GEMMs) + WgT for gate
  transpose_kernel<0><<<dim3(96, 32, 1), blk, 0, stream>>>(Wqkv, WqkvTh, WqkvTl, 1024, 3072);
  transpose_kernel<0><<<dim3(32, 32, 1), blk, 0, stream>>>(Wo, WoTh, WoTl, 1024, 1024);
  transpose_kernel<1><<<dim3(128, 32, 8), blk, 0, stream>>>(W1, W1T, nullptr, 1024, 4096);
  transpose_kernel<1><<<dim3(32, 128, 8), blk, 0, stream>>>(W2, W2T, nullptr, 4096, 1024);
  wg_transpose<<<dim3(32), blk, 0, stream>>>(Wg, WgT);
  // LN1 -> h (f16 hi/lo)
  ln_kernel<<<dim3(4096), blk, 0, stream>>>(x, ln1g, ln1b, hh, hl);
  // QKV = h @ Wqkv (split-f16 x3, 512 thr) -> f32
  gemm_kernel<0><<<dim3(24, 32), blk512, 0, stream>>>(hh, hl, WqkvTh, WqkvTl, 1024, 3072, 0,
                                                      nullptr, nullptr, nullptr, nullptr,
                                                      qkv, nullptr, nullptr, nullptr);
  // K/V pre-convert to split-f16 planes
  kv_prep<<<dim3(16, 16, 4), blk, 0, stream>>>(qkv, Kh, Kl, Vth, Vtl);
  // flash attention (balanced causal pairing: each block does 17 tile-steps)
  attn_kernel<<<dim3(8, 16, 4), blk, 0, stream>>>(qkv, Kh, Kl, Vth, Vtl, atth, attl);
  // x_resid = x + attn @ Wo (split-f16 x3, TN=64, 512 thr) -> d_out
  gemm_kernel<1><<<dim3(16, 32), blk512, 0, stream>>>(atth, attl, WoTh, WoTl, 1024, 1024, 0,
                                                      nullptr, nullptr, nullptr, nullptr,
                                                      out, nullptr, x, nullptr);
  // routing (f32, WgT coalesced, no atomics) + fused LN2 -> moein
  gate_kernel<<<dim3(1024), blk, 0, stream>>>(out, ln2g, ln2b, WgT, tok_e, tok_w, moein);
  // plan: histogram tok_e + tile table + cursor init (single block)
  plan_kernel<<<dim3(1), blk, 0, stream>>>(tok_e, cursor, tile_e, tile_b, tile_c);
  // scatter: deterministic per-expert ballot-scan compaction (grid 8, no atomics)
  scatter_kernel<<<dim3(8), blk, 0, stream>>>(tok_e, tok_w, cursor, lists, slotw);
  // FFN1: gather tokens, gelu(h @ W1[e]) -> act bf16 (TN=128, XCD-chunked, 512 thr)
  gemm_kernel<2><<<dim3(8 * 9 * 32), blk512, 0, stream>>>(moein, nullptr, W1T, nullptr, 1024, 4096, 4096,
                                                          lists, tile_e, tile_b, tile_c,
                                                          nullptr, act, nullptr, nullptr);
  // FFN2: act @ W2[e] * gate -> ypart scatter (TN=128, XCD-chunked, 512 thr)
  gemm_kernel<3><<<dim3(8 * 9 * 8), blk512, 0, stream>>>(act, nullptr, W2T, nullptr, 4096, 1024, 1024,
                                                         lists, tile_e, tile_b, tile_c,
                                                         ypart, nullptr, nullptr, slotw);
  // out = x_resid + y0 + y1
  combine_kernel<<<dim3(4096), blk, 0, stream>>>(out, ypart);
}